// Round 1
// baseline (997.262 us; speedup 1.0000x reference)
//
#include <hip/hip_runtime.h>
#include <math.h>

#define NN 4096

// ---------- helpers ----------
__device__ __forceinline__ unsigned encf(float f) {
  unsigned u = __float_as_uint(f);
  return (u & 0x80000000u) ? ~u : (u | 0x80000000u);
}
__device__ __forceinline__ float decf(unsigned u) {
  return __uint_as_float((u & 0x80000000u) ? (u ^ 0x80000000u) : ~u);
}

// ---------- init ----------
__global__ void k_init(float* out, unsigned* dmax) {
  int t = blockIdx.x * 256 + threadIdx.x;
  if (t < 512) out[t] = 0.f;
  if (t == 0) *dmax = 0u;
}

// ---------- pos = img @ Wp + bp ----------
__global__ void k_pos(const float* img, const float* Wp, const float* bp, float* pos) {
  int t = blockIdx.x * 256 + threadIdx.x;
  if (t >= NN * 12) return;
  int i = t / 12, d = t % 12;
  float s = bp[d];
#pragma unroll
  for (int k = 0; k < 6; ++k) s += img[i * 6 + k] * Wp[k * 12 + d];
  pos[t] = s;
}

// ---------- attention: out[i] = softmax(pos@pos^T/sqrt(12))[i] @ pos ----------
__global__ __launch_bounds__(256) void k_attn(const float* pos, float* out) {
  __shared__ float sc[NN];
  __shared__ float red[256];
  int i = blockIdx.x, t = threadIdx.x;
  float pi[12];
#pragma unroll
  for (int d = 0; d < 12; ++d) pi[d] = pos[i * 12 + d];
  float lmax = -1e30f;
  for (int j = t; j < NN; j += 256) {
    float s = 0.f;
#pragma unroll
    for (int d = 0; d < 12; ++d) s += pi[d] * pos[j * 12 + d];
    s *= 0.28867513459481287f;  // 1/sqrt(12)
    sc[j] = s;
    lmax = fmaxf(lmax, s);
  }
  red[t] = lmax; __syncthreads();
  for (int s = 128; s > 0; s >>= 1) { if (t < s) red[t] = fmaxf(red[t], red[t + s]); __syncthreads(); }
  float m = red[0]; __syncthreads();

  float acc[12] = {0,0,0,0,0,0,0,0,0,0,0,0};
  float lsum = 0.f;
  for (int j = t; j < NN; j += 256) {
    float e = expf(sc[j] - m);
    lsum += e;
#pragma unroll
    for (int d = 0; d < 12; ++d) acc[d] += e * pos[j * 12 + d];
  }
  red[t] = lsum; __syncthreads();
  for (int s = 128; s > 0; s >>= 1) { if (t < s) red[t] += red[t + s]; __syncthreads(); }
  float Z = red[0]; __syncthreads();
  for (int d = 0; d < 12; ++d) {
    red[t] = acc[d]; __syncthreads();
    for (int s = 128; s > 0; s >>= 1) { if (t < s) red[t] += red[t + s]; __syncthreads(); }
    if (t == 0) out[i * 12 + d] = red[0] / Z;
    __syncthreads();
  }
}

// ---------- layernorm feature (500) -> x0[:, 0:500] ----------
__global__ __launch_bounds__(256) void k_lnf(const float* f, const float* g, const float* b, float* x0) {
  __shared__ float row[500];
  __shared__ float red[256];
  int i = blockIdx.x, t = threadIdx.x;
  float ls = 0.f;
  for (int c = t; c < 500; c += 256) { float v = f[i * 500 + c]; row[c] = v; ls += v; }
  red[t] = ls; __syncthreads();
  for (int s = 128; s > 0; s >>= 1) { if (t < s) red[t] += red[t + s]; __syncthreads(); }
  float m = red[0] * (1.f / 500.f); __syncthreads();
  float lv = 0.f;
  for (int c = t; c < 500; c += 256) { float d = row[c] - m; lv += d * d; }
  red[t] = lv; __syncthreads();
  for (int s = 128; s > 0; s >>= 1) { if (t < s) red[t] += red[t + s]; __syncthreads(); }
  float var = red[0] * (1.f / 500.f);
  float scale = 1.f / sqrtf(var + 1e-5f);
  for (int c = t; c < 500; c += 256) x0[(size_t)i * 512 + c] = (row[c] - m) * scale * g[c] + b[c];
}

// ---------- layernorm pos (12) -> x0[:, 500:512] ----------
__global__ void k_lnp(const float* p, const float* g, const float* b, float* x0) {
  int i = blockIdx.x * 256 + threadIdx.x;
  if (i >= NN) return;
  float v[12], m = 0.f;
#pragma unroll
  for (int d = 0; d < 12; ++d) { v[d] = p[i * 12 + d]; m += v[d]; }
  m *= (1.f / 12.f);
  float var = 0.f;
#pragma unroll
  for (int d = 0; d < 12; ++d) { float dd = v[d] - m; var += dd * dd; }
  var *= (1.f / 12.f);
  float scale = 1.f / sqrtf(var + 1e-5f);
#pragma unroll
  for (int d = 0; d < 12; ++d) x0[(size_t)i * 512 + 500 + d] = (v[d] - m) * scale * g[d] + b[d];
}

// ---------- sq[i] = sum_c x0[i][c]^2 ----------
__global__ __launch_bounds__(256) void k_sq(const float* x0, float* sqv) {
  __shared__ float red[256];
  int i = blockIdx.x, t = threadIdx.x;
  float a = x0[(size_t)i * 512 + t], b = x0[(size_t)i * 512 + 256 + t];
  red[t] = a * a + b * b; __syncthreads();
  for (int s = 128; s > 0; s >>= 1) { if (t < s) red[t] += red[t + s]; __syncthreads(); }
  if (t == 0) sqv[i] = red[0];
}

// ---------- d2 tiles (upper triangular tile pairs): max pass / mask pass ----------
template <bool MASK>
__global__ __launch_bounds__(256) void k_d2(const float* X, const float* sqv,
                                            unsigned* dmax, unsigned char* ATm) {
  __shared__ float As[64][17];
  __shared__ float Bs[64][17];
  __shared__ float red[256];
  __shared__ unsigned char msk[64][64];
  const int NT = NN / 64;
  int bid = blockIdx.x, ti = 0, rem = bid;
  while (rem >= NT - ti) { rem -= NT - ti; ++ti; }
  int tj = ti + rem;
  int t = threadIdx.x, tx = t & 15, ty = t >> 4;
  float acc[4][4] = {};
  const float* Arow = X + (size_t)ti * 64 * 512;
  const float* Brow = X + (size_t)tj * 64 * 512;
  for (int k0 = 0; k0 < 512; k0 += 16) {
#pragma unroll
    for (int q = 0; q < 4; ++q) {
      int l = t + q * 256; int r = l >> 4, c = l & 15;
      As[r][c] = Arow[(size_t)r * 512 + k0 + c];
      Bs[r][c] = Brow[(size_t)r * 512 + k0 + c];
    }
    __syncthreads();
#pragma unroll
    for (int kk = 0; kk < 16; ++kk) {
      float av[4], bv[4];
#pragma unroll
      for (int u = 0; u < 4; ++u) { av[u] = As[ty * 4 + u][kk]; bv[u] = Bs[tx * 4 + u][kk]; }
#pragma unroll
      for (int a = 0; a < 4; ++a)
#pragma unroll
        for (int b2 = 0; b2 < 4; ++b2) acc[a][b2] = fmaf(av[a], bv[b2], acc[a][b2]);
    }
    __syncthreads();
  }
  float sqi[4], sqj[4];
#pragma unroll
  for (int u = 0; u < 4; ++u) { sqi[u] = sqv[ti * 64 + ty * 4 + u]; sqj[u] = sqv[tj * 64 + tx * 4 + u]; }
  if (!MASK) {
    float lm = -1e30f;
#pragma unroll
    for (int a = 0; a < 4; ++a)
#pragma unroll
      for (int b2 = 0; b2 < 4; ++b2) {
        float d2v = sqi[a] - 2.f * acc[a][b2] + sqj[b2];
        lm = fmaxf(lm, d2v);
      }
    red[t] = lm; __syncthreads();
    for (int s = 128; s > 0; s >>= 1) { if (t < s) red[t] = fmaxf(red[t], red[t + s]); __syncthreads(); }
    if (t == 0) atomicMax(dmax, encf(red[0]));
  } else {
    float thr = 0.5f * decf(*dmax);
#pragma unroll
    for (int a = 0; a < 4; ++a)
#pragma unroll
      for (int b2 = 0; b2 < 4; ++b2) {
        int gi = ti * 64 + ty * 4 + a, gj = tj * 64 + tx * 4 + b2;
        float d2v = sqi[a] - 2.f * acc[a][b2] + sqj[b2];
        msk[tx * 4 + b2][ty * 4 + a] = (d2v < thr && gi < gj) ? 1 : 0;
      }
    __syncthreads();
#pragma unroll
    for (int q = 0; q < 16; ++q) {
      int l = t + q * 256; int jl = l >> 6, il = l & 63;
      ATm[(size_t)(tj * 64 + jl) * NN + ti * 64 + il] = msk[jl][il];
    }
  }
}

// ---------- generic fp32 GEMM: C[M,N] = A[M,K] @ B[K,N]; M%64==0, N%64==0, K%16==0 ----------
__global__ __launch_bounds__(256) void k_gemm(const float* A, const float* B, float* C,
                                              int M, int N, int K) {
  __shared__ float As[64][17];
  __shared__ float Bs[16][64];
  int t = threadIdx.x, tx = t & 15, ty = t >> 4;
  int m0 = blockIdx.y * 64, n0 = blockIdx.x * 64;
  float acc[4][4] = {};
  for (int k0 = 0; k0 < K; k0 += 16) {
#pragma unroll
    for (int q = 0; q < 4; ++q) {
      int l = t + q * 256; int r = l >> 4, c = l & 15;
      As[r][c] = A[(size_t)(m0 + r) * K + k0 + c];
    }
#pragma unroll
    for (int q = 0; q < 4; ++q) {
      int l = t + q * 256; int r = l >> 6, c = l & 63;
      Bs[r][c] = B[(size_t)(k0 + r) * N + n0 + c];
    }
    __syncthreads();
#pragma unroll
    for (int kk = 0; kk < 16; ++kk) {
      float av[4], bv[4];
#pragma unroll
      for (int u = 0; u < 4; ++u) { av[u] = As[ty * 4 + u][kk]; bv[u] = Bs[kk][tx * 4 + u]; }
#pragma unroll
      for (int a = 0; a < 4; ++a)
#pragma unroll
        for (int b2 = 0; b2 < 4; ++b2) acc[a][b2] = fmaf(av[a], bv[b2], acc[a][b2]);
    }
    __syncthreads();
  }
#pragma unroll
  for (int a = 0; a < 4; ++a)
#pragma unroll
    for (int b2 = 0; b2 < 4; ++b2)
      C[(size_t)(m0 + ty * 4 + a) * N + n0 + tx * 4 + b2] = acc[a][b2];
}

// ---------- dinv[j] = 1/sqrt(1 + sum_i AT[j][i]) ----------
__global__ __launch_bounds__(256) void k_deg(const unsigned char* ATm, float* dinv, int n) {
  int w = threadIdx.x >> 6, lane = threadIdx.x & 63;
  int j = blockIdx.x * 4 + w;
  if (j >= n) return;
  const uint4* row = (const uint4*)(ATm + (size_t)j * n);
  int sum = 0;
  for (int p = lane; p < n / 16; p += 64) {
    uint4 v = row[p];
    unsigned a = v.x, b = v.y, c = v.z, d = v.w;
    sum += (a & 0xff) + ((a >> 8) & 0xff) + ((a >> 16) & 0xff) + (a >> 24);
    sum += (b & 0xff) + ((b >> 8) & 0xff) + ((b >> 16) & 0xff) + (b >> 24);
    sum += (c & 0xff) + ((c >> 8) & 0xff) + ((c >> 16) & 0xff) + (c >> 24);
    sum += (d & 0xff) + ((d >> 8) & 0xff) + ((d >> 16) & 0xff) + (d >> 24);
  }
  for (int s = 32; s > 0; s >>= 1) sum += __shfl_down(sum, s);
  if (lane == 0) dinv[j] = 1.f / sqrtf((float)(1 + sum));
}

// ---------- y[i][c] = dinv[i] * xW[i][c] ----------
__global__ void k_y(const float* xW, const float* dinv, float* y, int n) {
  int t = blockIdx.x * 256 + threadIdx.x;
  if (t < n * 256) y[t] = dinv[t >> 8] * xW[t];
}

// ---------- out[j][c] = relu(dinv[j]*(y[j][c] + sum_{i:AT[j,i]} y[i][c]) + b[c]) ----------
__global__ __launch_bounds__(256) void k_agg(const float* y, const unsigned char* ATm,
                                             const float* dinv, const float* bias,
                                             float* out, int n) {
  __shared__ unsigned char mrow[256];
  __shared__ int s_any;
  int j = blockIdx.x, t = threadIdx.x;
  float acc = y[(size_t)j * 256 + t];
  for (int i0 = 0; i0 < n; i0 += 256) {
    if (t == 0) s_any = 0;
    __syncthreads();
    unsigned char m = ATm[(size_t)j * n + i0 + t];
    mrow[t] = m;
    if (m) s_any = 1;
    __syncthreads();
    if (s_any) {
      for (int u = 0; u < 256; ++u)
        if (mrow[u]) acc += y[(size_t)(i0 + u) * 256 + t];
    }
    __syncthreads();
  }
  float o = dinv[j] * acc + bias[t];
  out[(size_t)j * 256 + t] = fmaxf(o, 0.f);
}

// ---------- y2[i] = dinv[i] * dot(xg[i], Wpool) ----------
__global__ __launch_bounds__(256) void k_xwp(const float* xg, const float* Wp,
                                             const float* dinv, float* y2, int n) {
  int w = threadIdx.x >> 6, lane = threadIdx.x & 63;
  int i = blockIdx.x * 4 + w;
  if (i >= n) return;
  float s = 0.f;
#pragma unroll
  for (int q = 0; q < 4; ++q) { int c = lane + q * 64; s += xg[(size_t)i * 256 + c] * Wp[c]; }
  for (int sh = 32; sh > 0; sh >>= 1) s += __shfl_down(s, sh);
  if (lane == 0) y2[i] = dinv[i] * s;
}

// ---------- score[j] = tanh(dinv[j]*(y2[j] + sum_{i:AT[j,i]} y2[i]) + bpool) ----------
__global__ __launch_bounds__(256) void k_scorek(const float* y2, const unsigned char* ATm,
                                                const float* dinv, const float* bp,
                                                float* score, int n) {
  int w = threadIdx.x >> 6, lane = threadIdx.x & 63;
  int j = blockIdx.x * 4 + w;
  if (j >= n) return;
  const unsigned char* row = ATm + (size_t)j * n;
  float s = 0.f;
  for (int i = lane; i < n; i += 64)
    if (row[i]) s += y2[i];
  for (int sh = 32; sh > 0; sh >>= 1) s += __shfl_down(s, sh);
  if (lane == 0) score[j] = tanhf(dinv[j] * (y2[j] + s) + bp[0]);
}

// ---------- full bitonic sort (desc, stable by index) -> perm, vals ----------
__global__ __launch_bounds__(1024) void k_topk(const float* score, int n, int k,
                                               int* perm, float* vals) {
  __shared__ unsigned long long keys[4096];
  int t = threadIdx.x;
  for (int i = t; i < 4096; i += 1024) {
    unsigned long long kv = 0ull;
    if (i < n) {
      unsigned u = encf(score[i]);
      kv = ((unsigned long long)u << 32) | (unsigned)(~i);
    }
    keys[i] = kv;
  }
  __syncthreads();
  for (int size = 2; size <= 4096; size <<= 1) {
    for (int stride = size >> 1; stride > 0; stride >>= 1) {
      for (int i = t; i < 4096; i += 1024) {
        int j = i ^ stride;
        if (j > i) {
          bool desc = ((i & size) == 0);
          unsigned long long a = keys[i], b = keys[j];
          bool sw = desc ? (a < b) : (a > b);
          if (sw) { keys[i] = b; keys[j] = a; }
        }
      }
      __syncthreads();
    }
  }
  for (int r = t; r < k; r += 1024) {
    unsigned idx = ~(unsigned)(keys[r] & 0xffffffffull);
    perm[r] = (int)idx;
    vals[r] = score[idx];
  }
}

// ---------- xp[r][c] = xg[perm[r]][c] * vals[r] ----------
__global__ void k_gatherx(const float* xg, const int* perm, const float* vals,
                          float* xp, int k) {
  int t = blockIdx.x * 256 + threadIdx.x;
  if (t >= k * 256) return;
  int r = t >> 8, c = t & 255;
  xp[t] = xg[(size_t)perm[r] * 256 + c] * vals[r];
}

// ---------- ATnew[c][r] = ATold[perm[c]][perm[r]] ----------
__global__ __launch_bounds__(256) void k_gatherA(const unsigned char* ATold, const int* perm,
                                                 unsigned char* ATnew, int nold, int kn) {
  __shared__ int sperm[4096];
  int t = threadIdx.x, c = blockIdx.x;
  for (int r = t; r < kn; r += 256) sperm[r] = perm[r];
  __syncthreads();
  const unsigned char* row = ATold + (size_t)sperm[c] * nold;
  unsigned char* orow = ATnew + (size_t)c * kn;
  for (int r = t; r < kn; r += 256) orow[r] = row[sperm[r]];
}

// ---------- readout partials / final ----------
__global__ __launch_bounds__(256) void k_rpart(const float* xp, float* pmax, float* psum, int k) {
  int b = blockIdx.x, t = threadIdx.x;
  float m = -1e30f, s = 0.f;
  for (int r = b; r < k; r += 16) { float v = xp[(size_t)r * 256 + t]; m = fmaxf(m, v); s += v; }
  pmax[b * 256 + t] = m; psum[b * 256 + t] = s;
}
__global__ void k_rfin(const float* pmax, const float* psum, float* out, int k) {
  int t = threadIdx.x;
  float m = -1e30f, s = 0.f;
  for (int q = 0; q < 16; ++q) { m = fmaxf(m, pmax[q * 256 + t]); s += psum[q * 256 + t]; }
  out[t] += m;
  out[256 + t] += s / (float)k;
}

// ---------- host-side layer driver ----------
static void run_layer(hipStream_t stream, const float* x_in, int n, int inC,
                      const float* W, const float* b, const float* Wpool, const float* bpool,
                      int k, const unsigned char* ATcur, unsigned char* ATnext, int /*unused*/,
                      float* xW, float* ybuf, float* xg, float* xp, float* dinv, float* y2,
                      float* score, int* perm, float* vals, float* pmax, float* psum, float* out) {
  k_deg<<<n / 4, 256, 0, stream>>>(ATcur, dinv, n);
  k_gemm<<<dim3(256 / 64, n / 64), 256, 0, stream>>>(x_in, W, xW, n, 256, inC);
  k_y<<<n, 256, 0, stream>>>(xW, dinv, ybuf, n);
  k_agg<<<n, 256, 0, stream>>>(ybuf, ATcur, dinv, b, xg, n);
  k_xwp<<<n / 4, 256, 0, stream>>>(xg, Wpool, dinv, y2, n);
  k_scorek<<<n / 4, 256, 0, stream>>>(y2, ATcur, dinv, bpool, score, n);
  k_topk<<<1, 1024, 0, stream>>>(score, n, k, perm, vals);
  k_gatherx<<<k, 256, 0, stream>>>(xg, perm, vals, xp, k);
  k_rpart<<<16, 256, 0, stream>>>(xp, pmax, psum, k);
  k_rfin<<<1, 256, 0, stream>>>(pmax, psum, out, k);
  if (ATnext) k_gatherA<<<k, 256, 0, stream>>>(ATcur, perm, ATnext, n, k);
}

extern "C" void kernel_launch(void* const* d_in, const int* in_sizes, int n_in,
                              void* d_out, int out_size, void* d_ws, size_t ws_size,
                              hipStream_t stream) {
  const float* feature = (const float*)d_in[0];
  const float* img     = (const float*)d_in[1];
  const float* Wp      = (const float*)d_in[2];
  const float* bp      = (const float*)d_in[3];
  const float* ln_f_g  = (const float*)d_in[4];
  const float* ln_f_b  = (const float*)d_in[5];
  const float* ln_p_g  = (const float*)d_in[6];
  const float* ln_p_b  = (const float*)d_in[7];
  const float* W1 = (const float*)d_in[8];   const float* b1 = (const float*)d_in[9];
  const float* Wpool1 = (const float*)d_in[10]; const float* bpool1 = (const float*)d_in[11];
  const float* W2 = (const float*)d_in[12];  const float* b2 = (const float*)d_in[13];
  const float* Wpool2 = (const float*)d_in[14]; const float* bpool2 = (const float*)d_in[15];
  const float* W3 = (const float*)d_in[16];  const float* b3 = (const float*)d_in[17];
  const float* Wpool3 = (const float*)d_in[18]; const float* bpool3 = (const float*)d_in[19];
  float* out = (float*)d_out;
  (void)in_sizes; (void)n_in; (void)out_size; (void)ws_size;

  char* w = (char*)d_ws;
  size_t off = 0;
  auto alloc = [&](size_t bytes) -> char* {
    off = (off + 255) & ~(size_t)255;
    char* p = w + off;
    off += bytes;
    return p;
  };
  float* pos0 = (float*)alloc((size_t)NN * 12 * 4);
  float* pos1 = (float*)alloc((size_t)NN * 12 * 4);
  float* x0   = (float*)alloc((size_t)NN * 512 * 4);
  float* sqv  = (float*)alloc((size_t)NN * 4);
  unsigned* dmax = (unsigned*)alloc(4);
  float* dinv = (float*)alloc((size_t)NN * 4);
  float* xW   = (float*)alloc((size_t)NN * 256 * 4);
  float* ybuf = (float*)alloc((size_t)NN * 256 * 4);
  float* xg   = (float*)alloc((size_t)NN * 256 * 4);
  float* xp   = (float*)alloc((size_t)NN * 256 * 4);
  float* y2   = (float*)alloc((size_t)NN * 4);
  float* score= (float*)alloc((size_t)NN * 4);
  int*   perm = (int*)alloc((size_t)NN * 4);
  float* vals = (float*)alloc((size_t)NN * 4);
  float* pmax = (float*)alloc(16 * 256 * 4);
  float* psum = (float*)alloc(16 * 256 * 4);
  unsigned char* ATa = (unsigned char*)alloc((size_t)NN * NN);
  unsigned char* ATb = (unsigned char*)alloc((size_t)3072 * 3072);

  // preamble
  k_init<<<2, 256, 0, stream>>>(out, dmax);
  k_pos<<<(NN * 12 + 255) / 256, 256, 0, stream>>>(img, Wp, bp, pos0);
  k_attn<<<NN, 256, 0, stream>>>(pos0, pos1);
  k_lnf<<<NN, 256, 0, stream>>>(feature, ln_f_g, ln_f_b, x0);
  k_lnp<<<NN / 256, 256, 0, stream>>>(pos1, ln_p_g, ln_p_b, x0);
  k_sq<<<NN, 256, 0, stream>>>(x0, sqv);

  // edge construction: d2 max pass, then mask pass (upper tile pairs only)
  const int NT = NN / 64, TT = NT * (NT + 1) / 2;
  k_d2<false><<<TT, 256, 0, stream>>>(x0, sqv, dmax, nullptr);
  hipMemsetAsync(ATa, 0, (size_t)NN * NN, stream);
  k_d2<true><<<TT, 256, 0, stream>>>(x0, sqv, dmax, ATa);

  // three GCN + SAGPool + readout layers
  run_layer(stream, x0, 4096, 512, W1, b1, Wpool1, bpool1, 3072, ATa, ATb, 0,
            xW, ybuf, xg, xp, dinv, y2, score, perm, vals, pmax, psum, out);
  run_layer(stream, xp, 3072, 256, W2, b2, Wpool2, bpool2, 2304, ATb, ATa, 0,
            xW, ybuf, xg, xp, dinv, y2, score, perm, vals, pmax, psum, out);
  run_layer(stream, xp, 2304, 256, W3, b3, Wpool3, bpool3, 1728, ATa, nullptr, 0,
            xW, ybuf, xg, xp, dinv, y2, score, perm, vals, pmax, psum, out);
}

// Round 2
// 688.354 us; speedup vs baseline: 1.4488x; 1.4488x over previous
//
#include <hip/hip_runtime.h>
#include <math.h>

#define NN 4096

typedef __attribute__((ext_vector_type(8))) short bf16x8;
typedef __attribute__((ext_vector_type(4))) float f32x4;

// ---------- helpers ----------
__device__ __forceinline__ unsigned encf(float f) {
  unsigned u = __float_as_uint(f);
  return (u & 0x80000000u) ? ~u : (u | 0x80000000u);
}
__device__ __forceinline__ float decf(unsigned u) {
  return __uint_as_float((u & 0x80000000u) ? (u ^ 0x80000000u) : ~u);
}
__device__ __forceinline__ unsigned short f2bf(float f) {
  unsigned u = __float_as_uint(f);
  return (unsigned short)((u + 0x7fffu + ((u >> 16) & 1u)) >> 16);
}

// ---------- init ----------
__global__ void k_init(float* out, unsigned* dmax) {
  int t = blockIdx.x * 256 + threadIdx.x;
  if (t < 512) out[t] = 0.f;
  if (t == 0) *dmax = 0u;
}

// ---------- pos = img @ Wp + bp ----------
__global__ void k_pos(const float* img, const float* Wp, const float* bp, float* pos) {
  int t = blockIdx.x * 256 + threadIdx.x;
  if (t >= NN * 12) return;
  int i = t / 12, d = t % 12;
  float s = bp[d];
#pragma unroll
  for (int k = 0; k < 6; ++k) s += img[i * 6 + k] * Wp[k * 12 + d];
  pos[t] = s;
}

// ---------- attention: out[i] = softmax(pos@pos^T/sqrt(12))[i] @ pos ----------
__global__ __launch_bounds__(256) void k_attn(const float* pos, float* out) {
  __shared__ float sc[NN];
  __shared__ float wred[4][13];
  int i = blockIdx.x, t = threadIdx.x, lane = t & 63, w = t >> 6;
  float pi[12];
#pragma unroll
  for (int d = 0; d < 12; ++d) pi[d] = pos[i * 12 + d];
  float lmax = -1e30f;
  for (int j = t; j < NN; j += 256) {
    float s = 0.f;
#pragma unroll
    for (int d = 0; d < 12; ++d) s = fmaf(pi[d], pos[j * 12 + d], s);
    s *= 0.28867513459481287f;  // 1/sqrt(12)
    sc[j] = s;
    lmax = fmaxf(lmax, s);
  }
#pragma unroll
  for (int o = 32; o > 0; o >>= 1) lmax = fmaxf(lmax, __shfl_xor(lmax, o));
  if (lane == 0) wred[w][12] = lmax;
  __syncthreads();
  float m = fmaxf(fmaxf(wred[0][12], wred[1][12]), fmaxf(wred[2][12], wred[3][12]));
  __syncthreads();  // all reads of wred done before reuse below

  float acc[12] = {0,0,0,0,0,0,0,0,0,0,0,0};
  float lsum = 0.f;
  for (int j = t; j < NN; j += 256) {
    float e = expf(sc[j] - m);
    lsum += e;
#pragma unroll
    for (int d = 0; d < 12; ++d) acc[d] = fmaf(e, pos[j * 12 + d], acc[d]);
  }
#pragma unroll
  for (int o = 32; o > 0; o >>= 1) {
    lsum += __shfl_xor(lsum, o);
#pragma unroll
    for (int d = 0; d < 12; ++d) acc[d] += __shfl_xor(acc[d], o);
  }
  if (lane == 0) {
#pragma unroll
    for (int d = 0; d < 12; ++d) wred[w][d] = acc[d];
    wred[w][12] = lsum;
  }
  __syncthreads();
  if (t < 12) {
    float Z = wred[0][12] + wred[1][12] + wred[2][12] + wred[3][12];
    out[i * 12 + t] = (wred[0][t] + wred[1][t] + wred[2][t] + wred[3][t]) / Z;
  }
}

// ---------- layernorm feature (500) -> x0[:, 0:500] ----------
__global__ __launch_bounds__(256) void k_lnf(const float* f, const float* g, const float* b, float* x0) {
  __shared__ float row[500];
  __shared__ float red[256];
  int i = blockIdx.x, t = threadIdx.x;
  float ls = 0.f;
  for (int c = t; c < 500; c += 256) { float v = f[i * 500 + c]; row[c] = v; ls += v; }
  red[t] = ls; __syncthreads();
  for (int s = 128; s > 0; s >>= 1) { if (t < s) red[t] += red[t + s]; __syncthreads(); }
  float m = red[0] * (1.f / 500.f); __syncthreads();
  float lv = 0.f;
  for (int c = t; c < 500; c += 256) { float d = row[c] - m; lv += d * d; }
  red[t] = lv; __syncthreads();
  for (int s = 128; s > 0; s >>= 1) { if (t < s) red[t] += red[t + s]; __syncthreads(); }
  float var = red[0] * (1.f / 500.f);
  float scale = 1.f / sqrtf(var + 1e-5f);
  for (int c = t; c < 500; c += 256) x0[(size_t)i * 512 + c] = (row[c] - m) * scale * g[c] + b[c];
}

// ---------- layernorm pos (12) -> x0[:, 500:512] ----------
__global__ void k_lnp(const float* p, const float* g, const float* b, float* x0) {
  int i = blockIdx.x * 256 + threadIdx.x;
  if (i >= NN) return;
  float v[12], m = 0.f;
#pragma unroll
  for (int d = 0; d < 12; ++d) { v[d] = p[i * 12 + d]; m += v[d]; }
  m *= (1.f / 12.f);
  float var = 0.f;
#pragma unroll
  for (int d = 0; d < 12; ++d) { float dd = v[d] - m; var += dd * dd; }
  var *= (1.f / 12.f);
  float scale = 1.f / sqrtf(var + 1e-5f);
#pragma unroll
  for (int d = 0; d < 12; ++d) x0[(size_t)i * 512 + 500 + d] = (v[d] - m) * scale * g[d] + b[d];
}

// ---------- sq[i] = sum_c x0[i][c]^2 ----------
__global__ __launch_bounds__(256) void k_sq(const float* x0, float* sqv) {
  __shared__ float red[256];
  int i = blockIdx.x, t = threadIdx.x;
  float a = x0[(size_t)i * 512 + t], b = x0[(size_t)i * 512 + 256 + t];
  red[t] = a * a + b * b; __syncthreads();
  for (int s = 128; s > 0; s >>= 1) { if (t < s) red[t] += red[t + s]; __syncthreads(); }
  if (t == 0) sqv[i] = red[0];
}

// ---------- fp32 -> bf16 conversion (4 elems/thread) ----------
__global__ void k_cvt(const float* x, unsigned short* xh) {
  int t = blockIdx.x * 256 + threadIdx.x;  // t < NN*512/4
  float4 v = ((const float4*)x)[t];
  ushort4 h;
  h.x = f2bf(v.x); h.y = f2bf(v.y); h.z = f2bf(v.z); h.w = f2bf(v.w);
  ((ushort4*)xh)[t] = h;
}

// ---------- MFMA d2 tiles (128x128, upper tile pairs): max / mask pass ----------
// LDS row stride 40 bf16 = 80 bytes: keeps ds_read_b128 16B-aligned and bank-balanced.
#define LS 40
template <bool MASK>
__global__ __launch_bounds__(256) void k_d2m(const unsigned short* X, const float* sqv,
                                             unsigned* dmax, unsigned char* ATm) {
  __shared__ unsigned short As[128 * LS];
  __shared__ unsigned short Bs[128 * LS];
  const int NT = NN / 128;
  int bid = blockIdx.x, ti = 0, rem = bid;
  while (rem >= NT - ti) { rem -= NT - ti; ++ti; }
  int tj = ti + rem;
  int t = threadIdx.x, lane = t & 63, w = t >> 6;
  int wr = w >> 1, wc = w & 1;  // wave's 64x64 sub-tile
  f32x4 acc[4][4] = {};
  const unsigned short* Abase = X + (size_t)ti * 128 * 512;
  const unsigned short* Bbase = X + (size_t)tj * 128 * 512;
  for (int k0 = 0; k0 < 512; k0 += 32) {
    __syncthreads();
#pragma unroll
    for (int q0 = 0; q0 < 2; ++q0) {
      int q = t + q0 * 256;          // 512 16B-chunks per panel
      int r = q >> 2, c = q & 3;     // row, 16B-chunk within row
      uint4 va = *(const uint4*)(Abase + (size_t)r * 512 + k0 + c * 8);
      uint4 vb = *(const uint4*)(Bbase + (size_t)r * 512 + k0 + c * 8);
      *(uint4*)(&As[r * LS + c * 8]) = va;
      *(uint4*)(&Bs[r * LS + c * 8]) = vb;
    }
    __syncthreads();
    bf16x8 af[4], bq[4];
    int kc = (lane >> 4) * 8, rl = lane & 15;
#pragma unroll
    for (int f = 0; f < 4; ++f) {
      af[f] = *(const bf16x8*)(&As[(wr * 64 + f * 16 + rl) * LS + kc]);
      bq[f] = *(const bf16x8*)(&Bs[(wc * 64 + f * 16 + rl) * LS + kc]);
    }
#pragma unroll
    for (int a = 0; a < 4; ++a)
#pragma unroll
      for (int b = 0; b < 4; ++b)
        acc[a][b] = __builtin_amdgcn_mfma_f32_16x16x32_bf16(af[a], bq[b], acc[a][b], 0, 0, 0);
  }
  // C/D layout: col = lane&15, row = (lane>>4)*4 + reg   [m89/m91 verified]
  int rbase = ti * 128 + wr * 64 + ((lane >> 4) << 2);
  int cbase = tj * 128 + wc * 64 + (lane & 15);
  if (!MASK) {
    float lm = -1e30f;
#pragma unroll
    for (int a = 0; a < 4; ++a) {
      float si[4];
#pragma unroll
      for (int r = 0; r < 4; ++r) si[r] = sqv[rbase + a * 16 + r];
#pragma unroll
      for (int b = 0; b < 4; ++b) {
        float sj = sqv[cbase + b * 16];
#pragma unroll
        for (int r = 0; r < 4; ++r)
          lm = fmaxf(lm, si[r] - 2.f * acc[a][b][r] + sj);
      }
    }
#pragma unroll
    for (int o = 32; o > 0; o >>= 1) lm = fmaxf(lm, __shfl_xor(lm, o));
    if (lane == 0) atomicMax(dmax, encf(lm));
  } else {
    float thr = 0.5f * decf(*dmax);
#pragma unroll
    for (int b = 0; b < 4; ++b) {
      int gj = cbase + b * 16;
      float sj = sqv[gj];
#pragma unroll
      for (int a = 0; a < 4; ++a) {
        int gi0 = rbase + a * 16;
        union { unsigned char c[4]; unsigned u; } m4;
#pragma unroll
        for (int r = 0; r < 4; ++r) {
          float d2v = sqv[gi0 + r] - 2.f * acc[a][b][r] + sj;
          m4.c[r] = (d2v < thr && (gi0 + r) < gj) ? 1 : 0;
        }
        *(unsigned*)(ATm + (size_t)gj * NN + gi0) = m4.u;  // AT[j][i..i+3]
      }
    }
  }
}

// ---------- generic fp32 GEMM: C[M,N] = A[M,K] @ B[K,N]; M%64==0, N%64==0, K%16==0 ----------
__global__ __launch_bounds__(256) void k_gemm(const float* A, const float* B, float* C,
                                              int M, int N, int K) {
  __shared__ float As[64][17];
  __shared__ float Bs[16][64];
  int t = threadIdx.x, tx = t & 15, ty = t >> 4;
  int m0 = blockIdx.y * 64, n0 = blockIdx.x * 64;
  float acc[4][4] = {};
  for (int k0 = 0; k0 < K; k0 += 16) {
#pragma unroll
    for (int q = 0; q < 4; ++q) {
      int l = t + q * 256; int r = l >> 4, c = l & 15;
      As[r][c] = A[(size_t)(m0 + r) * K + k0 + c];
    }
#pragma unroll
    for (int q = 0; q < 4; ++q) {
      int l = t + q * 256; int r = l >> 6, c = l & 63;
      Bs[r][c] = B[(size_t)(k0 + r) * N + n0 + c];
    }
    __syncthreads();
#pragma unroll
    for (int kk = 0; kk < 16; ++kk) {
      float av[4], bv[4];
#pragma unroll
      for (int u = 0; u < 4; ++u) { av[u] = As[ty * 4 + u][kk]; bv[u] = Bs[kk][tx * 4 + u]; }
#pragma unroll
      for (int a = 0; a < 4; ++a)
#pragma unroll
        for (int b2 = 0; b2 < 4; ++b2) acc[a][b2] = fmaf(av[a], bv[b2], acc[a][b2]);
    }
    __syncthreads();
  }
#pragma unroll
  for (int a = 0; a < 4; ++a)
#pragma unroll
    for (int b2 = 0; b2 < 4; ++b2)
      C[(size_t)(m0 + ty * 4 + a) * N + n0 + tx * 4 + b2] = acc[a][b2];
}

// ---------- dinv[j] = 1/sqrt(1 + sum_i AT[j][i]) ----------
__global__ __launch_bounds__(256) void k_deg(const unsigned char* ATm, float* dinv, int n) {
  int w = threadIdx.x >> 6, lane = threadIdx.x & 63;
  int j = blockIdx.x * 4 + w;
  if (j >= n) return;
  const uint4* row = (const uint4*)(ATm + (size_t)j * n);
  int sum = 0;
  for (int p = lane; p < n / 16; p += 64) {
    uint4 v = row[p];
    unsigned a = v.x, b = v.y, c = v.z, d = v.w;
    sum += (a & 0xff) + ((a >> 8) & 0xff) + ((a >> 16) & 0xff) + (a >> 24);
    sum += (b & 0xff) + ((b >> 8) & 0xff) + ((b >> 16) & 0xff) + (b >> 24);
    sum += (c & 0xff) + ((c >> 8) & 0xff) + ((c >> 16) & 0xff) + (c >> 24);
    sum += (d & 0xff) + ((d >> 8) & 0xff) + ((d >> 16) & 0xff) + (d >> 24);
  }
  for (int s = 32; s > 0; s >>= 1) sum += __shfl_down(sum, s);
  if (lane == 0) dinv[j] = 1.f / sqrtf((float)(1 + sum));
}

// ---------- y[i][c] = dinv[i] * xW[i][c] ----------
__global__ void k_y(const float* xW, const float* dinv, float* y, int n) {
  int t = blockIdx.x * 256 + threadIdx.x;
  if (t < n * 256) y[t] = dinv[t >> 8] * xW[t];
}

// ---------- out[j][c] = relu(dinv[j]*(y[j][c] + sum_{i:AT[j,i]} y[i][c]) + b[c]) ----------
__global__ __launch_bounds__(256) void k_agg(const float* y, const unsigned char* ATm,
                                             const float* dinv, const float* bias,
                                             float* out, int n) {
  __shared__ unsigned char mrow[256];
  __shared__ int s_any;
  int j = blockIdx.x, t = threadIdx.x;
  float acc = y[(size_t)j * 256 + t];
  for (int i0 = 0; i0 < n; i0 += 256) {
    if (t == 0) s_any = 0;
    __syncthreads();
    unsigned char m = ATm[(size_t)j * n + i0 + t];
    mrow[t] = m;
    if (m) s_any = 1;
    __syncthreads();
    if (s_any) {
      for (int u = 0; u < 256; ++u)
        if (mrow[u]) acc += y[(size_t)(i0 + u) * 256 + t];
    }
    __syncthreads();
  }
  float o = dinv[j] * acc + bias[t];
  out[(size_t)j * 256 + t] = fmaxf(o, 0.f);
}

// ---------- y2[i] = dinv[i] * dot(xg[i], Wpool) ----------
__global__ __launch_bounds__(256) void k_xwp(const float* xg, const float* Wp,
                                             const float* dinv, float* y2, int n) {
  int w = threadIdx.x >> 6, lane = threadIdx.x & 63;
  int i = blockIdx.x * 4 + w;
  if (i >= n) return;
  float s = 0.f;
#pragma unroll
  for (int q = 0; q < 4; ++q) { int c = lane + q * 64; s += xg[(size_t)i * 256 + c] * Wp[c]; }
  for (int sh = 32; sh > 0; sh >>= 1) s += __shfl_down(s, sh);
  if (lane == 0) y2[i] = dinv[i] * s;
}

// ---------- score[j] = tanh(dinv[j]*(y2[j] + sum_{i:AT[j,i]} y2[i]) + bpool) ----------
__global__ __launch_bounds__(256) void k_scorek(const float* y2, const unsigned char* ATm,
                                                const float* dinv, const float* bp,
                                                float* score, int n) {
  int w = threadIdx.x >> 6, lane = threadIdx.x & 63;
  int j = blockIdx.x * 4 + w;
  if (j >= n) return;
  const unsigned char* row = ATm + (size_t)j * n;
  float s = 0.f;
  for (int i = lane; i < n; i += 64)
    if (row[i]) s += y2[i];
  for (int sh = 32; sh > 0; sh >>= 1) s += __shfl_down(s, sh);
  if (lane == 0) score[j] = tanhf(dinv[j] * (y2[j] + s) + bp[0]);
}

// ---------- full bitonic sort (desc, stable by index) -> perm, vals ----------
__global__ __launch_bounds__(1024) void k_topk(const float* score, int n, int k,
                                               int* perm, float* vals) {
  __shared__ unsigned long long keys[4096];
  int t = threadIdx.x;
  for (int i = t; i < 4096; i += 1024) {
    unsigned long long kv = 0ull;
    if (i < n) {
      unsigned u = encf(score[i]);
      kv = ((unsigned long long)u << 32) | (unsigned)(~i);
    }
    keys[i] = kv;
  }
  __syncthreads();
  for (int size = 2; size <= 4096; size <<= 1) {
    for (int stride = size >> 1; stride > 0; stride >>= 1) {
      for (int i = t; i < 4096; i += 1024) {
        int j = i ^ stride;
        if (j > i) {
          bool desc = ((i & size) == 0);
          unsigned long long a = keys[i], b = keys[j];
          bool sw = desc ? (a < b) : (a > b);
          if (sw) { keys[i] = b; keys[j] = a; }
        }
      }
      __syncthreads();
    }
  }
  for (int r = t; r < k; r += 1024) {
    unsigned idx = ~(unsigned)(keys[r] & 0xffffffffull);
    perm[r] = (int)idx;
    vals[r] = score[idx];
  }
}

// ---------- xp[r][c] = xg[perm[r]][c] * vals[r] ----------
__global__ void k_gatherx(const float* xg, const int* perm, const float* vals,
                          float* xp, int k) {
  int t = blockIdx.x * 256 + threadIdx.x;
  if (t >= k * 256) return;
  int r = t >> 8, c = t & 255;
  xp[t] = xg[(size_t)perm[r] * 256 + c] * vals[r];
}

// ---------- ATnew[c][r] = ATold[perm[c]][perm[r]] ----------
__global__ __launch_bounds__(256) void k_gatherA(const unsigned char* ATold, const int* perm,
                                                 unsigned char* ATnew, int nold, int kn) {
  __shared__ int sperm[4096];
  int t = threadIdx.x, c = blockIdx.x;
  for (int r = t; r < kn; r += 256) sperm[r] = perm[r];
  __syncthreads();
  const unsigned char* row = ATold + (size_t)sperm[c] * nold;
  unsigned char* orow = ATnew + (size_t)c * kn;
  for (int r = t; r < kn; r += 256) orow[r] = row[sperm[r]];
}

// ---------- readout partials / final ----------
__global__ __launch_bounds__(256) void k_rpart(const float* xp, float* pmax, float* psum, int k) {
  int b = blockIdx.x, t = threadIdx.x;
  float m = -1e30f, s = 0.f;
  for (int r = b; r < k; r += 16) { float v = xp[(size_t)r * 256 + t]; m = fmaxf(m, v); s += v; }
  pmax[b * 256 + t] = m; psum[b * 256 + t] = s;
}
__global__ void k_rfin(const float* pmax, const float* psum, float* out, int k) {
  int t = threadIdx.x;
  float m = -1e30f, s = 0.f;
  for (int q = 0; q < 16; ++q) { m = fmaxf(m, pmax[q * 256 + t]); s += psum[q * 256 + t]; }
  out[t] += m;
  out[256 + t] += s / (float)k;
}

// ---------- host-side layer driver ----------
static void run_layer(hipStream_t stream, const float* x_in, int n, int inC,
                      const float* W, const float* b, const float* Wpool, const float* bpool,
                      int k, const unsigned char* ATcur, unsigned char* ATnext,
                      float* xW, float* ybuf, float* xg, float* xp, float* dinv, float* y2,
                      float* score, int* perm, float* vals, float* pmax, float* psum, float* out) {
  k_deg<<<n / 4, 256, 0, stream>>>(ATcur, dinv, n);
  k_gemm<<<dim3(256 / 64, n / 64), 256, 0, stream>>>(x_in, W, xW, n, 256, inC);
  k_y<<<n, 256, 0, stream>>>(xW, dinv, ybuf, n);
  k_agg<<<n, 256, 0, stream>>>(ybuf, ATcur, dinv, b, xg, n);
  k_xwp<<<n / 4, 256, 0, stream>>>(xg, Wpool, dinv, y2, n);
  k_scorek<<<n / 4, 256, 0, stream>>>(y2, ATcur, dinv, bpool, score, n);
  k_topk<<<1, 1024, 0, stream>>>(score, n, k, perm, vals);
  k_gatherx<<<k, 256, 0, stream>>>(xg, perm, vals, xp, k);
  k_rpart<<<16, 256, 0, stream>>>(xp, pmax, psum, k);
  k_rfin<<<1, 256, 0, stream>>>(pmax, psum, out, k);
  if (ATnext) k_gatherA<<<k, 256, 0, stream>>>(ATcur, perm, ATnext, n, k);
}

extern "C" void kernel_launch(void* const* d_in, const int* in_sizes, int n_in,
                              void* d_out, int out_size, void* d_ws, size_t ws_size,
                              hipStream_t stream) {
  const float* feature = (const float*)d_in[0];
  const float* img     = (const float*)d_in[1];
  const float* Wp      = (const float*)d_in[2];
  const float* bp      = (const float*)d_in[3];
  const float* ln_f_g  = (const float*)d_in[4];
  const float* ln_f_b  = (const float*)d_in[5];
  const float* ln_p_g  = (const float*)d_in[6];
  const float* ln_p_b  = (const float*)d_in[7];
  const float* W1 = (const float*)d_in[8];   const float* b1 = (const float*)d_in[9];
  const float* Wpool1 = (const float*)d_in[10]; const float* bpool1 = (const float*)d_in[11];
  const float* W2 = (const float*)d_in[12];  const float* b2 = (const float*)d_in[13];
  const float* Wpool2 = (const float*)d_in[14]; const float* bpool2 = (const float*)d_in[15];
  const float* W3 = (const float*)d_in[16];  const float* b3 = (const float*)d_in[17];
  const float* Wpool3 = (const float*)d_in[18]; const float* bpool3 = (const float*)d_in[19];
  float* out = (float*)d_out;
  (void)in_sizes; (void)n_in; (void)out_size; (void)ws_size;

  char* w = (char*)d_ws;
  size_t off = 0;
  auto alloc = [&](size_t bytes) -> char* {
    off = (off + 255) & ~(size_t)255;
    char* p = w + off;
    off += bytes;
    return p;
  };
  float* pos0 = (float*)alloc((size_t)NN * 12 * 4);
  float* pos1 = (float*)alloc((size_t)NN * 12 * 4);
  float* x0   = (float*)alloc((size_t)NN * 512 * 4);
  unsigned short* x0h = (unsigned short*)alloc((size_t)NN * 512 * 2);
  float* sqv  = (float*)alloc((size_t)NN * 4);
  unsigned* dmax = (unsigned*)alloc(4);
  float* dinv = (float*)alloc((size_t)NN * 4);
  float* xW   = (float*)alloc((size_t)NN * 256 * 4);
  float* ybuf = (float*)alloc((size_t)NN * 256 * 4);
  float* xg   = (float*)alloc((size_t)NN * 256 * 4);
  float* xp   = (float*)alloc((size_t)NN * 256 * 4);
  float* y2   = (float*)alloc((size_t)NN * 4);
  float* score= (float*)alloc((size_t)NN * 4);
  int*   perm = (int*)alloc((size_t)NN * 4);
  float* vals = (float*)alloc((size_t)NN * 4);
  float* pmax = (float*)alloc(16 * 256 * 4);
  float* psum = (float*)alloc(16 * 256 * 4);
  unsigned char* ATa = (unsigned char*)alloc((size_t)NN * NN);
  unsigned char* ATb = (unsigned char*)alloc((size_t)3072 * 3072);

  // preamble
  k_init<<<2, 256, 0, stream>>>(out, dmax);
  k_pos<<<(NN * 12 + 255) / 256, 256, 0, stream>>>(img, Wp, bp, pos0);
  k_attn<<<NN, 256, 0, stream>>>(pos0, pos1);
  k_lnf<<<NN, 256, 0, stream>>>(feature, ln_f_g, ln_f_b, x0);
  k_lnp<<<NN / 256, 256, 0, stream>>>(pos1, ln_p_g, ln_p_b, x0);
  k_sq<<<NN, 256, 0, stream>>>(x0, sqv);
  k_cvt<<<NN * 512 / 4 / 256, 256, 0, stream>>>(x0, x0h);

  // edge construction via MFMA: max pass, then mask pass (upper 128-tile pairs)
  const int NT = NN / 128, TT = NT * (NT + 1) / 2;
  k_d2m<false><<<TT, 256, 0, stream>>>(x0h, sqv, dmax, nullptr);
  hipMemsetAsync(ATa, 0, (size_t)NN * NN, stream);
  k_d2m<true><<<TT, 256, 0, stream>>>(x0h, sqv, dmax, ATa);

  // three GCN + SAGPool + readout layers
  run_layer(stream, x0, 4096, 512, W1, b1, Wpool1, bpool1, 3072, ATa, ATb,
            xW, ybuf, xg, xp, dinv, y2, score, perm, vals, pmax, psum, out);
  run_layer(stream, xp, 3072, 256, W2, b2, Wpool2, bpool2, 2304, ATb, ATa,
            xW, ybuf, xg, xp, dinv, y2, score, perm, vals, pmax, psum, out);
  run_layer(stream, xp, 2304, 256, W3, b3, Wpool3, bpool3, 1728, ATa, nullptr,
            xW, ybuf, xg, xp, dinv, y2, score, perm, vals, pmax, psum, out);
}

// Round 3
// 530.381 us; speedup vs baseline: 1.8803x; 1.2978x over previous
//
#include <hip/hip_runtime.h>
#include <math.h>

#define NN 4096

typedef __attribute__((ext_vector_type(8))) short bf16x8;
typedef __attribute__((ext_vector_type(4))) float f32x4;

// ---------- helpers ----------
__device__ __forceinline__ unsigned encf(float f) {
  unsigned u = __float_as_uint(f);
  return (u & 0x80000000u) ? ~u : (u | 0x80000000u);
}
__device__ __forceinline__ float decf(unsigned u) {
  return __uint_as_float((u & 0x80000000u) ? (u ^ 0x80000000u) : ~u);
}
__device__ __forceinline__ unsigned short f2bf(float f) {
  unsigned u = __float_as_uint(f);
  return (unsigned short)((u + 0x7fffu + ((u >> 16) & 1u)) >> 16);
}

// ---------- init ----------
__global__ void k_init(float* out, unsigned* dmax) {
  int t = blockIdx.x * 256 + threadIdx.x;
  if (t < 512) out[t] = 0.f;
  if (t == 0) *dmax = 0u;
}

// ---------- pos = img @ Wp + bp ----------
__global__ void k_pos(const float* img, const float* Wp, const float* bp, float* pos) {
  int t = blockIdx.x * 256 + threadIdx.x;
  if (t >= NN * 12) return;
  int i = t / 12, d = t % 12;
  float s = bp[d];
#pragma unroll
  for (int k = 0; k < 6; ++k) s += img[i * 6 + k] * Wp[k * 12 + d];
  pos[t] = s;
}

// ---------- attention: out[i] = softmax(pos@pos^T/sqrt(12))[i] @ pos ----------
__global__ __launch_bounds__(256) void k_attn(const float* pos, float* out) {
  __shared__ float sc[NN];
  __shared__ float wred[4][13];
  int i = blockIdx.x, t = threadIdx.x, lane = t & 63, w = t >> 6;
  float pi[12];
#pragma unroll
  for (int d = 0; d < 12; ++d) pi[d] = pos[i * 12 + d];
  float lmax = -1e30f;
  for (int j = t; j < NN; j += 256) {
    float s = 0.f;
#pragma unroll
    for (int d = 0; d < 12; ++d) s = fmaf(pi[d], pos[j * 12 + d], s);
    s *= 0.28867513459481287f;  // 1/sqrt(12)
    sc[j] = s;
    lmax = fmaxf(lmax, s);
  }
#pragma unroll
  for (int o = 32; o > 0; o >>= 1) lmax = fmaxf(lmax, __shfl_xor(lmax, o));
  if (lane == 0) wred[w][12] = lmax;
  __syncthreads();
  float m = fmaxf(fmaxf(wred[0][12], wred[1][12]), fmaxf(wred[2][12], wred[3][12]));
  __syncthreads();  // all reads of wred done before reuse below

  float acc[12] = {0,0,0,0,0,0,0,0,0,0,0,0};
  float lsum = 0.f;
  for (int j = t; j < NN; j += 256) {
    float e = expf(sc[j] - m);
    lsum += e;
#pragma unroll
    for (int d = 0; d < 12; ++d) acc[d] = fmaf(e, pos[j * 12 + d], acc[d]);
  }
#pragma unroll
  for (int o = 32; o > 0; o >>= 1) {
    lsum += __shfl_xor(lsum, o);
#pragma unroll
    for (int d = 0; d < 12; ++d) acc[d] += __shfl_xor(acc[d], o);
  }
  if (lane == 0) {
#pragma unroll
    for (int d = 0; d < 12; ++d) wred[w][d] = acc[d];
    wred[w][12] = lsum;
  }
  __syncthreads();
  if (t < 12) {
    float Z = wred[0][12] + wred[1][12] + wred[2][12] + wred[3][12];
    out[i * 12 + t] = (wred[0][t] + wred[1][t] + wred[2][t] + wred[3][t]) / Z;
  }
}

// ---------- layernorm feature (500) -> x0[:, 0:500] ----------
__global__ __launch_bounds__(256) void k_lnf(const float* f, const float* g, const float* b, float* x0) {
  __shared__ float row[500];
  __shared__ float red[256];
  int i = blockIdx.x, t = threadIdx.x;
  float ls = 0.f;
  for (int c = t; c < 500; c += 256) { float v = f[i * 500 + c]; row[c] = v; ls += v; }
  red[t] = ls; __syncthreads();
  for (int s = 128; s > 0; s >>= 1) { if (t < s) red[t] += red[t + s]; __syncthreads(); }
  float m = red[0] * (1.f / 500.f); __syncthreads();
  float lv = 0.f;
  for (int c = t; c < 500; c += 256) { float d = row[c] - m; lv += d * d; }
  red[t] = lv; __syncthreads();
  for (int s = 128; s > 0; s >>= 1) { if (t < s) red[t] += red[t + s]; __syncthreads(); }
  float var = red[0] * (1.f / 500.f);
  float scale = 1.f / sqrtf(var + 1e-5f);
  for (int c = t; c < 500; c += 256) x0[(size_t)i * 512 + c] = (row[c] - m) * scale * g[c] + b[c];
}

// ---------- layernorm pos (12) -> x0[:, 500:512] ----------
__global__ void k_lnp(const float* p, const float* g, const float* b, float* x0) {
  int i = blockIdx.x * 256 + threadIdx.x;
  if (i >= NN) return;
  float v[12], m = 0.f;
#pragma unroll
  for (int d = 0; d < 12; ++d) { v[d] = p[i * 12 + d]; m += v[d]; }
  m *= (1.f / 12.f);
  float var = 0.f;
#pragma unroll
  for (int d = 0; d < 12; ++d) { float dd = v[d] - m; var += dd * dd; }
  var *= (1.f / 12.f);
  float scale = 1.f / sqrtf(var + 1e-5f);
#pragma unroll
  for (int d = 0; d < 12; ++d) x0[(size_t)i * 512 + 500 + d] = (v[d] - m) * scale * g[d] + b[d];
}

// ---------- sq[i] = sum_c x0[i][c]^2 ----------
__global__ __launch_bounds__(256) void k_sq(const float* x0, float* sqv) {
  __shared__ float red[256];
  int i = blockIdx.x, t = threadIdx.x;
  float a = x0[(size_t)i * 512 + t], b = x0[(size_t)i * 512 + 256 + t];
  red[t] = a * a + b * b; __syncthreads();
  for (int s = 128; s > 0; s >>= 1) { if (t < s) red[t] += red[t + s]; __syncthreads(); }
  if (t == 0) sqv[i] = red[0];
}

// ---------- fp32 -> bf16 conversion (4 elems/thread) ----------
__global__ void k_cvt(const float* x, unsigned short* xh) {
  int t = blockIdx.x * 256 + threadIdx.x;  // t < NN*512/4
  float4 v = ((const float4*)x)[t];
  ushort4 h;
  h.x = f2bf(v.x); h.y = f2bf(v.y); h.z = f2bf(v.z); h.w = f2bf(v.w);
  ((ushort4*)xh)[t] = h;
}

// ---------- MFMA d2 tiles (128x128, upper tile pairs): max / mask pass ----------
// LDS row stride 40 bf16 = 80 bytes: keeps ds_read_b128 16B-aligned and bank-balanced.
#define LS 40
template <bool MASK>
__global__ __launch_bounds__(256) void k_d2m(const unsigned short* X, const float* sqv,
                                             unsigned* dmax, unsigned char* ATm) {
  __shared__ unsigned short As[128 * LS];
  __shared__ unsigned short Bs[128 * LS];
  const int NT = NN / 128;
  int bid = blockIdx.x, ti = 0, rem = bid;
  while (rem >= NT - ti) { rem -= NT - ti; ++ti; }
  int tj = ti + rem;
  int t = threadIdx.x, lane = t & 63, w = t >> 6;
  int wr = w >> 1, wc = w & 1;  // wave's 64x64 sub-tile
  f32x4 acc[4][4] = {};
  const unsigned short* Abase = X + (size_t)ti * 128 * 512;
  const unsigned short* Bbase = X + (size_t)tj * 128 * 512;
  for (int k0 = 0; k0 < 512; k0 += 32) {
    __syncthreads();
#pragma unroll
    for (int q0 = 0; q0 < 2; ++q0) {
      int q = t + q0 * 256;          // 512 16B-chunks per panel
      int r = q >> 2, c = q & 3;     // row, 16B-chunk within row
      uint4 va = *(const uint4*)(Abase + (size_t)r * 512 + k0 + c * 8);
      uint4 vb = *(const uint4*)(Bbase + (size_t)r * 512 + k0 + c * 8);
      *(uint4*)(&As[r * LS + c * 8]) = va;
      *(uint4*)(&Bs[r * LS + c * 8]) = vb;
    }
    __syncthreads();
    bf16x8 af[4], bq[4];
    int kc = (lane >> 4) * 8, rl = lane & 15;
#pragma unroll
    for (int f = 0; f < 4; ++f) {
      af[f] = *(const bf16x8*)(&As[(wr * 64 + f * 16 + rl) * LS + kc]);
      bq[f] = *(const bf16x8*)(&Bs[(wc * 64 + f * 16 + rl) * LS + kc]);
    }
#pragma unroll
    for (int a = 0; a < 4; ++a)
#pragma unroll
      for (int b = 0; b < 4; ++b)
        acc[a][b] = __builtin_amdgcn_mfma_f32_16x16x32_bf16(af[a], bq[b], acc[a][b], 0, 0, 0);
  }
  // C/D layout: col = lane&15, row = (lane>>4)*4 + reg   [m89/m91 verified]
  int rbase = ti * 128 + wr * 64 + ((lane >> 4) << 2);
  int cbase = tj * 128 + wc * 64 + (lane & 15);
  if (!MASK) {
    float lm = -1e30f;
#pragma unroll
    for (int a = 0; a < 4; ++a) {
      float si[4];
#pragma unroll
      for (int r = 0; r < 4; ++r) si[r] = sqv[rbase + a * 16 + r];
#pragma unroll
      for (int b = 0; b < 4; ++b) {
        float sj = sqv[cbase + b * 16];
#pragma unroll
        for (int r = 0; r < 4; ++r)
          lm = fmaxf(lm, si[r] - 2.f * acc[a][b][r] + sj);
      }
    }
#pragma unroll
    for (int o = 32; o > 0; o >>= 1) lm = fmaxf(lm, __shfl_xor(lm, o));
    if (lane == 0) atomicMax(dmax, encf(lm));
  } else {
    float thr = 0.5f * decf(*dmax);
#pragma unroll
    for (int b = 0; b < 4; ++b) {
      int gj = cbase + b * 16;
      float sj = sqv[gj];
#pragma unroll
      for (int a = 0; a < 4; ++a) {
        int gi0 = rbase + a * 16;
        union { unsigned char c[4]; unsigned u; } m4;
#pragma unroll
        for (int r = 0; r < 4; ++r) {
          float d2v = sqv[gi0 + r] - 2.f * acc[a][b][r] + sj;
          m4.c[r] = (d2v < thr && (gi0 + r) < gj) ? 1 : 0;
        }
        *(unsigned*)(ATm + (size_t)gj * NN + gi0) = m4.u;  // AT[j][i..i+3]
      }
    }
  }
}

// ---------- generic fp32 GEMM: C[M,N] = A[M,K] @ B[K,N]; M%64==0, N%64==0, K%16==0 ----------
__global__ __launch_bounds__(256) void k_gemm(const float* A, const float* B, float* C,
                                              int M, int N, int K) {
  __shared__ float As[64][17];
  __shared__ float Bs[16][64];
  int t = threadIdx.x, tx = t & 15, ty = t >> 4;
  int m0 = blockIdx.y * 64, n0 = blockIdx.x * 64;
  float acc[4][4] = {};
  for (int k0 = 0; k0 < K; k0 += 16) {
#pragma unroll
    for (int q = 0; q < 4; ++q) {
      int l = t + q * 256; int r = l >> 4, c = l & 15;
      As[r][c] = A[(size_t)(m0 + r) * K + k0 + c];
    }
#pragma unroll
    for (int q = 0; q < 4; ++q) {
      int l = t + q * 256; int r = l >> 6, c = l & 63;
      Bs[r][c] = B[(size_t)(k0 + r) * N + n0 + c];
    }
    __syncthreads();
#pragma unroll
    for (int kk = 0; kk < 16; ++kk) {
      float av[4], bv[4];
#pragma unroll
      for (int u = 0; u < 4; ++u) { av[u] = As[ty * 4 + u][kk]; bv[u] = Bs[kk][tx * 4 + u]; }
#pragma unroll
      for (int a = 0; a < 4; ++a)
#pragma unroll
        for (int b2 = 0; b2 < 4; ++b2) acc[a][b2] = fmaf(av[a], bv[b2], acc[a][b2]);
    }
    __syncthreads();
  }
#pragma unroll
  for (int a = 0; a < 4; ++a)
#pragma unroll
    for (int b2 = 0; b2 < 4; ++b2)
      C[(size_t)(m0 + ty * 4 + a) * N + n0 + tx * 4 + b2] = acc[a][b2];
}

// ---------- dinv[j] = 1/sqrt(1 + sum_i AT[j][i]) ----------
__global__ __launch_bounds__(256) void k_deg(const unsigned char* ATm, float* dinv, int n) {
  int w = threadIdx.x >> 6, lane = threadIdx.x & 63;
  int j = blockIdx.x * 4 + w;
  if (j >= n) return;
  const uint4* row = (const uint4*)(ATm + (size_t)j * n);
  int sum = 0;
  for (int p = lane; p < n / 16; p += 64) {
    uint4 v = row[p];
    unsigned a = v.x, b = v.y, c = v.z, d = v.w;
    sum += (a & 0xff) + ((a >> 8) & 0xff) + ((a >> 16) & 0xff) + (a >> 24);
    sum += (b & 0xff) + ((b >> 8) & 0xff) + ((b >> 16) & 0xff) + (b >> 24);
    sum += (c & 0xff) + ((c >> 8) & 0xff) + ((c >> 16) & 0xff) + (c >> 24);
    sum += (d & 0xff) + ((d >> 8) & 0xff) + ((d >> 16) & 0xff) + (d >> 24);
  }
  for (int s = 32; s > 0; s >>= 1) sum += __shfl_down(sum, s);
  if (lane == 0) dinv[j] = 1.f / sqrtf((float)(1 + sum));
}

// ---------- y[i][c] = dinv[i] * xW[i][c] ----------
__global__ void k_y(const float* xW, const float* dinv, float* y, int n) {
  int t = blockIdx.x * 256 + threadIdx.x;
  if (t < n * 256) y[t] = dinv[t >> 8] * xW[t];
}

// ---------- out[j][c] = relu(dinv[j]*(y[j][c] + sum_{i:AT[j,i]} y[i][c]) + b[c]) ----------
__global__ __launch_bounds__(256) void k_agg(const float* y, const unsigned char* ATm,
                                             const float* dinv, const float* bias,
                                             float* out, int n) {
  __shared__ unsigned char mrow[256];
  __shared__ int s_any;
  int j = blockIdx.x, t = threadIdx.x;
  float acc = y[(size_t)j * 256 + t];
  for (int i0 = 0; i0 < n; i0 += 256) {
    if (t == 0) s_any = 0;
    __syncthreads();
    unsigned char m = ATm[(size_t)j * n + i0 + t];
    mrow[t] = m;
    if (m) s_any = 1;
    __syncthreads();
    if (s_any) {
      for (int u = 0; u < 256; ++u)
        if (mrow[u]) acc += y[(size_t)(i0 + u) * 256 + t];
    }
    __syncthreads();
  }
  float o = dinv[j] * acc + bias[t];
  out[(size_t)j * 256 + t] = fmaxf(o, 0.f);
}

// ---------- y2[i] = dinv[i] * dot(xg[i], Wpool) ----------
__global__ __launch_bounds__(256) void k_xwp(const float* xg, const float* Wp,
                                             const float* dinv, float* y2, int n) {
  int w = threadIdx.x >> 6, lane = threadIdx.x & 63;
  int i = blockIdx.x * 4 + w;
  if (i >= n) return;
  float s = 0.f;
#pragma unroll
  for (int q = 0; q < 4; ++q) { int c = lane + q * 64; s += xg[(size_t)i * 256 + c] * Wp[c]; }
  for (int sh = 32; sh > 0; sh >>= 1) s += __shfl_down(s, sh);
  if (lane == 0) y2[i] = dinv[i] * s;
}

// ---------- score[j] = tanh(dinv[j]*(y2[j] + sum_{i:AT[j,i]} y2[i]) + bpool) ----------
__global__ __launch_bounds__(256) void k_scorek(const float* y2, const unsigned char* ATm,
                                                const float* dinv, const float* bp,
                                                float* score, int n) {
  int w = threadIdx.x >> 6, lane = threadIdx.x & 63;
  int j = blockIdx.x * 4 + w;
  if (j >= n) return;
  const unsigned char* row = ATm + (size_t)j * n;
  float s = 0.f;
  for (int i = lane; i < n; i += 64)
    if (row[i]) s += y2[i];
  for (int sh = 32; sh > 0; sh >>= 1) s += __shfl_down(s, sh);
  if (lane == 0) score[j] = tanhf(dinv[j] * (y2[j] + s) + bp[0]);
}

// ---------- radix-select top-k (exact PyG set semantics; output in index order) ----------
// Selected SET equals reference's (score desc, ties -> lower index). Order of perm is
// index-order, which is valid because all downstream consumers are permutation-
// equivariant and the readouts are permutation-invariant.
__global__ __launch_bounds__(1024) void k_topsel(const float* score, int n, int k,
                                                 int* perm, float* vals) {
  __shared__ unsigned keys[4096];
  __shared__ unsigned hist[256];
  __shared__ unsigned s_state[2];  // [0]=prefix(cutoff), [1]=need(ties to take)
  __shared__ unsigned woff[16];
  int t = threadIdx.x, lane = t & 63, w = t >> 6;
  for (int i = t; i < 4096; i += 1024) keys[i] = (i < n) ? encf(score[i]) : 0u;
  if (t == 0) { s_state[0] = 0u; s_state[1] = (unsigned)k; }
  __syncthreads();

  // 4 MSB-first radix passes to find the k-th largest key exactly
  for (int pass = 0; pass < 4; ++pass) {
    int shift = 24 - pass * 8;
    if (t < 256) hist[t] = 0u;
    __syncthreads();
    unsigned prefix = s_state[0];
    unsigned need = s_state[1];
    unsigned pmask = pass ? (0xFFFFFFFFu << (shift + 8)) : 0u;
    for (int i = t; i < n; i += 1024) {
      unsigned kk = keys[i];
      if ((kk & pmask) == prefix) atomicAdd(&hist[(kk >> shift) & 255u], 1u);
    }
    __syncthreads();
    if (w == 0) {
      unsigned h[4], suf[4];
#pragma unroll
      for (int r = 0; r < 4; ++r) h[r] = hist[lane * 4 + r];
      suf[3] = h[3]; suf[2] = h[2] + suf[3]; suf[1] = h[1] + suf[2]; suf[0] = h[0] + suf[1];
      unsigned lsum = suf[0];
      unsigned s = lsum;  // inclusive suffix-sum across lanes
#pragma unroll
      for (int off = 1; off < 64; off <<= 1) {
        unsigned o = __shfl_down(s, off);
        if (lane + off < 64) s += o;
      }
      unsigned Hl = s - lsum;  // contribution of lanes > lane
      int cand = -1; unsigned cumAt = 0, histAt = 0;
#pragma unroll
      for (int r = 0; r < 4; ++r) {
        unsigned c = Hl + suf[r];  // cum(4*lane+r) = count of keys with digit >= d
        if (c >= need) { cand = lane * 4 + r; cumAt = c; histAt = h[r]; }
      }
      int gmax = cand;
#pragma unroll
      for (int off = 32; off > 0; off >>= 1) {
        int o = __shfl_xor(gmax, off);
        gmax = o > gmax ? o : gmax;
      }
      if (cand == gmax && cand >= 0) {
        s_state[0] = prefix | ((unsigned)cand << shift);
        s_state[1] = need - (cumAt - histAt);  // minus count of strictly-larger digits
      }
    }
    __syncthreads();
  }
  unsigned cutoff = s_state[0];
  unsigned tcount = s_state[1];
  unsigned G = (unsigned)k - tcount;  // count of keys strictly > cutoff

  // compaction in index order: 4 contiguous elements per thread.
  // packed pair counts: (gt << 16) | eq  (each <= 4096, fits 16 bits)
  int i0 = t * 4;
  unsigned loc[4], cnt = 0;
#pragma unroll
  for (int r = 0; r < 4; ++r) {
    unsigned kk = keys[i0 + r];
    unsigned g = (kk > cutoff) ? 1u : 0u;
    unsigned e = (kk == cutoff) ? 1u : 0u;
    loc[r] = cnt;
    cnt += (g << 16) | e;
  }
  unsigned inc = cnt;  // wave inclusive scan
#pragma unroll
  for (int off = 1; off < 64; off <<= 1) {
    unsigned o = __shfl_up(inc, off);
    if (lane >= off) inc += o;
  }
  if (lane == 63) woff[w] = inc;
  __syncthreads();
  if (t == 0) {
    unsigned run = 0;
    for (int q = 0; q < 16; ++q) { unsigned v = woff[q]; woff[q] = run; run += v; }
  }
  __syncthreads();
  unsigned base = woff[w] + (inc - cnt);
#pragma unroll
  for (int r = 0; r < 4; ++r) {
    unsigned kk = keys[i0 + r];
    unsigned p = base + loc[r];
    if (kk > cutoff) {
      unsigned pos = p >> 16;
      perm[pos] = i0 + r; vals[pos] = decf(kk);
    } else if (kk == cutoff) {
      unsigned pe = p & 0xffffu;
      if (pe < tcount) { perm[G + pe] = i0 + r; vals[G + pe] = decf(kk); }
    }
  }
}

// ---------- xp[r][c] = xg[perm[r]][c] * vals[r] ----------
__global__ void k_gatherx(const float* xg, const int* perm, const float* vals,
                          float* xp, int k) {
  int t = blockIdx.x * 256 + threadIdx.x;
  if (t >= k * 256) return;
  int r = t >> 8, c = t & 255;
  xp[t] = xg[(size_t)perm[r] * 256 + c] * vals[r];
}

// ---------- ATnew[c][r] = ATold[perm[c]][perm[r]] ----------
__global__ __launch_bounds__(256) void k_gatherA(const unsigned char* ATold, const int* perm,
                                                 unsigned char* ATnew, int nold, int kn) {
  __shared__ int sperm[4096];
  int t = threadIdx.x, c = blockIdx.x;
  for (int r = t; r < kn; r += 256) sperm[r] = perm[r];
  __syncthreads();
  const unsigned char* row = ATold + (size_t)sperm[c] * nold;
  unsigned char* orow = ATnew + (size_t)c * kn;
  for (int r = t; r < kn; r += 256) orow[r] = row[sperm[r]];
}

// ---------- readout partials / final ----------
__global__ __launch_bounds__(256) void k_rpart(const float* xp, float* pmax, float* psum, int k) {
  int b = blockIdx.x, t = threadIdx.x;
  float m = -1e30f, s = 0.f;
  for (int r = b; r < k; r += 16) { float v = xp[(size_t)r * 256 + t]; m = fmaxf(m, v); s += v; }
  pmax[b * 256 + t] = m; psum[b * 256 + t] = s;
}
__global__ void k_rfin(const float* pmax, const float* psum, float* out, int k) {
  int t = threadIdx.x;
  float m = -1e30f, s = 0.f;
  for (int q = 0; q < 16; ++q) { m = fmaxf(m, pmax[q * 256 + t]); s += psum[q * 256 + t]; }
  out[t] += m;
  out[256 + t] += s / (float)k;
}

// ---------- host-side layer driver ----------
static void run_layer(hipStream_t stream, const float* x_in, int n, int inC,
                      const float* W, const float* b, const float* Wpool, const float* bpool,
                      int k, const unsigned char* ATcur, unsigned char* ATnext,
                      float* xW, float* ybuf, float* xg, float* xp, float* dinv, float* y2,
                      float* score, int* perm, float* vals, float* pmax, float* psum, float* out) {
  k_deg<<<n / 4, 256, 0, stream>>>(ATcur, dinv, n);
  k_gemm<<<dim3(256 / 64, n / 64), 256, 0, stream>>>(x_in, W, xW, n, 256, inC);
  k_y<<<n, 256, 0, stream>>>(xW, dinv, ybuf, n);
  k_agg<<<n, 256, 0, stream>>>(ybuf, ATcur, dinv, b, xg, n);
  k_xwp<<<n / 4, 256, 0, stream>>>(xg, Wpool, dinv, y2, n);
  k_scorek<<<n / 4, 256, 0, stream>>>(y2, ATcur, dinv, bpool, score, n);
  k_topsel<<<1, 1024, 0, stream>>>(score, n, k, perm, vals);
  k_gatherx<<<k, 256, 0, stream>>>(xg, perm, vals, xp, k);
  k_rpart<<<16, 256, 0, stream>>>(xp, pmax, psum, k);
  k_rfin<<<1, 256, 0, stream>>>(pmax, psum, out, k);
  if (ATnext) k_gatherA<<<k, 256, 0, stream>>>(ATcur, perm, ATnext, n, k);
}

extern "C" void kernel_launch(void* const* d_in, const int* in_sizes, int n_in,
                              void* d_out, int out_size, void* d_ws, size_t ws_size,
                              hipStream_t stream) {
  const float* feature = (const float*)d_in[0];
  const float* img     = (const float*)d_in[1];
  const float* Wp      = (const float*)d_in[2];
  const float* bp      = (const float*)d_in[3];
  const float* ln_f_g  = (const float*)d_in[4];
  const float* ln_f_b  = (const float*)d_in[5];
  const float* ln_p_g  = (const float*)d_in[6];
  const float* ln_p_b  = (const float*)d_in[7];
  const float* W1 = (const float*)d_in[8];   const float* b1 = (const float*)d_in[9];
  const float* Wpool1 = (const float*)d_in[10]; const float* bpool1 = (const float*)d_in[11];
  const float* W2 = (const float*)d_in[12];  const float* b2 = (const float*)d_in[13];
  const float* Wpool2 = (const float*)d_in[14]; const float* bpool2 = (const float*)d_in[15];
  const float* W3 = (const float*)d_in[16];  const float* b3 = (const float*)d_in[17];
  const float* Wpool3 = (const float*)d_in[18]; const float* bpool3 = (const float*)d_in[19];
  float* out = (float*)d_out;
  (void)in_sizes; (void)n_in; (void)out_size; (void)ws_size;

  char* w = (char*)d_ws;
  size_t off = 0;
  auto alloc = [&](size_t bytes) -> char* {
    off = (off + 255) & ~(size_t)255;
    char* p = w + off;
    off += bytes;
    return p;
  };
  float* pos0 = (float*)alloc((size_t)NN * 12 * 4);
  float* pos1 = (float*)alloc((size_t)NN * 12 * 4);
  float* x0   = (float*)alloc((size_t)NN * 512 * 4);
  unsigned short* x0h = (unsigned short*)alloc((size_t)NN * 512 * 2);
  float* sqv  = (float*)alloc((size_t)NN * 4);
  unsigned* dmax = (unsigned*)alloc(4);
  float* dinv = (float*)alloc((size_t)NN * 4);
  float* xW   = (float*)alloc((size_t)NN * 256 * 4);
  float* ybuf = (float*)alloc((size_t)NN * 256 * 4);
  float* xg   = (float*)alloc((size_t)NN * 256 * 4);
  float* xp   = (float*)alloc((size_t)NN * 256 * 4);
  float* y2   = (float*)alloc((size_t)NN * 4);
  float* score= (float*)alloc((size_t)NN * 4);
  int*   perm = (int*)alloc((size_t)NN * 4);
  float* vals = (float*)alloc((size_t)NN * 4);
  float* pmax = (float*)alloc(16 * 256 * 4);
  float* psum = (float*)alloc(16 * 256 * 4);
  unsigned char* ATa = (unsigned char*)alloc((size_t)NN * NN);
  unsigned char* ATb = (unsigned char*)alloc((size_t)3072 * 3072);

  // preamble
  k_init<<<2, 256, 0, stream>>>(out, dmax);
  k_pos<<<(NN * 12 + 255) / 256, 256, 0, stream>>>(img, Wp, bp, pos0);
  k_attn<<<NN, 256, 0, stream>>>(pos0, pos1);
  k_lnf<<<NN, 256, 0, stream>>>(feature, ln_f_g, ln_f_b, x0);
  k_lnp<<<NN / 256, 256, 0, stream>>>(pos1, ln_p_g, ln_p_b, x0);
  k_sq<<<NN, 256, 0, stream>>>(x0, sqv);
  k_cvt<<<NN * 512 / 4 / 256, 256, 0, stream>>>(x0, x0h);

  // edge construction via MFMA: max pass, then mask pass (upper 128-tile pairs)
  const int NT = NN / 128, TT = NT * (NT + 1) / 2;
  k_d2m<false><<<TT, 256, 0, stream>>>(x0h, sqv, dmax, nullptr);
  hipMemsetAsync(ATa, 0, (size_t)NN * NN, stream);
  k_d2m<true><<<TT, 256, 0, stream>>>(x0h, sqv, dmax, ATa);

  // three GCN + SAGPool + readout layers
  run_layer(stream, x0, 4096, 512, W1, b1, Wpool1, bpool1, 3072, ATa, ATb,
            xW, ybuf, xg, xp, dinv, y2, score, perm, vals, pmax, psum, out);
  run_layer(stream, xp, 3072, 256, W2, b2, Wpool2, bpool2, 2304, ATb, ATa,
            xW, ybuf, xg, xp, dinv, y2, score, perm, vals, pmax, psum, out);
  run_layer(stream, xp, 2304, 256, W3, b3, Wpool3, bpool3, 1728, ATa, nullptr,
            xW, ybuf, xg, xp, dinv, y2, score, perm, vals, pmax, psum, out);
}

// Round 4
// 517.828 us; speedup vs baseline: 1.9259x; 1.0242x over previous
//
#include <hip/hip_runtime.h>
#include <math.h>

#define NN 4096

typedef __attribute__((ext_vector_type(8))) short bf16x8;
typedef __attribute__((ext_vector_type(4))) float f32x4;

// ---------- helpers ----------
__device__ __forceinline__ unsigned encf(float f) {
  unsigned u = __float_as_uint(f);
  return (u & 0x80000000u) ? ~u : (u | 0x80000000u);
}
__device__ __forceinline__ float decf(unsigned u) {
  return __uint_as_float((u & 0x80000000u) ? (u ^ 0x80000000u) : ~u);
}
__device__ __forceinline__ unsigned short f2bf(float f) {
  unsigned u = __float_as_uint(f);
  return (unsigned short)((u + 0x7fffu + ((u >> 16) & 1u)) >> 16);
}

// ---------- init ----------
__global__ void k_init(float* out, unsigned* dmax) {
  int t = blockIdx.x * 256 + threadIdx.x;
  if (t < 512) out[t] = 0.f;
  if (t == 0) *dmax = 0u;
}

// ---------- pos = img @ Wp + bp ----------
__global__ void k_pos(const float* img, const float* Wp, const float* bp, float* pos) {
  int t = blockIdx.x * 256 + threadIdx.x;
  if (t >= NN * 12) return;
  int i = t / 12, d = t % 12;
  float s = bp[d];
#pragma unroll
  for (int k = 0; k < 6; ++k) s += img[i * 6 + k] * Wp[k * 12 + d];
  pos[t] = s;
}

// ---------- flash attention, d=12: out[i] = softmax(pos@pos^T/sqrt(12))[i] @ pos ----------
// 2 query rows per wave, online softmax per lane, merge across 64 lanes at end.
__global__ __launch_bounds__(256) void k_attn2(const float* pos, float* out) {
  int t = threadIdx.x, lane = t & 63, w = t >> 6;
  int ib = blockIdx.x * 8 + w * 2;  // 2 rows per wave, 8 per block
  float pi[2][12];
#pragma unroll
  for (int i = 0; i < 2; ++i)
#pragma unroll
    for (int d = 0; d < 12; ++d) pi[i][d] = pos[(ib + i) * 12 + d] * 0.28867513459481287f;
  float ml[2] = {-1e30f, -1e30f}, sl[2] = {0.f, 0.f};
  float acc[2][12] = {};
  const float4* p4 = (const float4*)pos;
  for (int j0 = 0; j0 < NN; j0 += 64) {
    int j = j0 + lane;
    float4 a = p4[j * 3 + 0], b = p4[j * 3 + 1], c = p4[j * 3 + 2];
    float pj[12] = {a.x, a.y, a.z, a.w, b.x, b.y, b.z, b.w, c.x, c.y, c.z, c.w};
#pragma unroll
    for (int i = 0; i < 2; ++i) {
      float s = 0.f;
#pragma unroll
      for (int d = 0; d < 12; ++d) s = fmaf(pi[i][d], pj[d], s);
      if (s > ml[i]) {
        float f = expf(ml[i] - s);
        sl[i] = fmaf(sl[i], f, 1.f);
#pragma unroll
        for (int d = 0; d < 12; ++d) acc[i][d] = fmaf(acc[i][d], f, pj[d]);
        ml[i] = s;
      } else {
        float e = expf(s - ml[i]);
        sl[i] += e;
#pragma unroll
        for (int d = 0; d < 12; ++d) acc[i][d] = fmaf(e, pj[d], acc[i][d]);
      }
    }
  }
#pragma unroll
  for (int i = 0; i < 2; ++i) {
    float gm = ml[i];
#pragma unroll
    for (int o = 32; o > 0; o >>= 1) gm = fmaxf(gm, __shfl_xor(gm, o));
    float f = expf(ml[i] - gm);
    float s = sl[i] * f;
#pragma unroll
    for (int o = 32; o > 0; o >>= 1) s += __shfl_xor(s, o);
    float ad[12];
#pragma unroll
    for (int d = 0; d < 12; ++d) {
      ad[d] = acc[i][d] * f;
#pragma unroll
      for (int o = 32; o > 0; o >>= 1) ad[d] += __shfl_xor(ad[d], o);
    }
    if (lane == 0) {
      float inv = 1.f / s;
#pragma unroll
      for (int d = 0; d < 12; ++d) out[(ib + i) * 12 + d] = ad[d] * inv;
    }
  }
}

// ---------- layernorm feature (500) -> x0[:, 0:500] ----------
__global__ __launch_bounds__(256) void k_lnf(const float* f, const float* g, const float* b, float* x0) {
  __shared__ float row[500];
  __shared__ float red[256];
  int i = blockIdx.x, t = threadIdx.x;
  float ls = 0.f;
  for (int c = t; c < 500; c += 256) { float v = f[i * 500 + c]; row[c] = v; ls += v; }
  red[t] = ls; __syncthreads();
  for (int s = 128; s > 0; s >>= 1) { if (t < s) red[t] += red[t + s]; __syncthreads(); }
  float m = red[0] * (1.f / 500.f); __syncthreads();
  float lv = 0.f;
  for (int c = t; c < 500; c += 256) { float d = row[c] - m; lv += d * d; }
  red[t] = lv; __syncthreads();
  for (int s = 128; s > 0; s >>= 1) { if (t < s) red[t] += red[t + s]; __syncthreads(); }
  float var = red[0] * (1.f / 500.f);
  float scale = 1.f / sqrtf(var + 1e-5f);
  for (int c = t; c < 500; c += 256) x0[(size_t)i * 512 + c] = (row[c] - m) * scale * g[c] + b[c];
}

// ---------- layernorm pos (12) -> x0[:, 500:512] ----------
__global__ void k_lnp(const float* p, const float* g, const float* b, float* x0) {
  int i = blockIdx.x * 256 + threadIdx.x;
  if (i >= NN) return;
  float v[12], m = 0.f;
#pragma unroll
  for (int d = 0; d < 12; ++d) { v[d] = p[i * 12 + d]; m += v[d]; }
  m *= (1.f / 12.f);
  float var = 0.f;
#pragma unroll
  for (int d = 0; d < 12; ++d) { float dd = v[d] - m; var += dd * dd; }
  var *= (1.f / 12.f);
  float scale = 1.f / sqrtf(var + 1e-5f);
#pragma unroll
  for (int d = 0; d < 12; ++d) x0[(size_t)i * 512 + 500 + d] = (v[d] - m) * scale * g[d] + b[d];
}

// ---------- sq[i] = sum_c x0[i][c]^2 ----------
__global__ __launch_bounds__(256) void k_sq(const float* x0, float* sqv) {
  __shared__ float red[256];
  int i = blockIdx.x, t = threadIdx.x;
  float a = x0[(size_t)i * 512 + t], b = x0[(size_t)i * 512 + 256 + t];
  red[t] = a * a + b * b; __syncthreads();
  for (int s = 128; s > 0; s >>= 1) { if (t < s) red[t] += red[t + s]; __syncthreads(); }
  if (t == 0) sqv[i] = red[0];
}

// ---------- fp32 -> bf16 conversion (4 elems/thread) ----------
__global__ void k_cvt(const float* x, unsigned short* xh) {
  int t = blockIdx.x * 256 + threadIdx.x;  // t < NN*512/4
  float4 v = ((const float4*)x)[t];
  ushort4 h;
  h.x = f2bf(v.x); h.y = f2bf(v.y); h.z = f2bf(v.z); h.w = f2bf(v.w);
  ((ushort4*)xh)[t] = h;
}

// ---------- MFMA d2 tiles (128x128, upper tile pairs): max / mask pass ----------
// LDS row stride 40 bf16 = 80 bytes: keeps ds_read_b128 16B-aligned and bank-balanced.
#define LS 40
template <bool MASK>
__global__ __launch_bounds__(256) void k_d2m(const unsigned short* X, const float* sqv,
                                             unsigned* dmax, unsigned char* ATm) {
  __shared__ unsigned short As[128 * LS];
  __shared__ unsigned short Bs[128 * LS];
  const int NT = NN / 128;
  int bid = blockIdx.x, ti = 0, rem = bid;
  while (rem >= NT - ti) { rem -= NT - ti; ++ti; }
  int tj = ti + rem;
  int t = threadIdx.x, lane = t & 63, w = t >> 6;
  int wr = w >> 1, wc = w & 1;  // wave's 64x64 sub-tile
  f32x4 acc[4][4] = {};
  const unsigned short* Abase = X + (size_t)ti * 128 * 512;
  const unsigned short* Bbase = X + (size_t)tj * 128 * 512;
  for (int k0 = 0; k0 < 512; k0 += 32) {
    __syncthreads();
#pragma unroll
    for (int q0 = 0; q0 < 2; ++q0) {
      int q = t + q0 * 256;          // 512 16B-chunks per panel
      int r = q >> 2, c = q & 3;     // row, 16B-chunk within row
      uint4 va = *(const uint4*)(Abase + (size_t)r * 512 + k0 + c * 8);
      uint4 vb = *(const uint4*)(Bbase + (size_t)r * 512 + k0 + c * 8);
      *(uint4*)(&As[r * LS + c * 8]) = va;
      *(uint4*)(&Bs[r * LS + c * 8]) = vb;
    }
    __syncthreads();
    bf16x8 af[4], bq[4];
    int kc = (lane >> 4) * 8, rl = lane & 15;
#pragma unroll
    for (int f = 0; f < 4; ++f) {
      af[f] = *(const bf16x8*)(&As[(wr * 64 + f * 16 + rl) * LS + kc]);
      bq[f] = *(const bf16x8*)(&Bs[(wc * 64 + f * 16 + rl) * LS + kc]);
    }
#pragma unroll
    for (int a = 0; a < 4; ++a)
#pragma unroll
      for (int b = 0; b < 4; ++b)
        acc[a][b] = __builtin_amdgcn_mfma_f32_16x16x32_bf16(af[a], bq[b], acc[a][b], 0, 0, 0);
  }
  // C/D layout: col = lane&15, row = (lane>>4)*4 + reg   [m89/m91 verified]
  int rbase = ti * 128 + wr * 64 + ((lane >> 4) << 2);
  int cbase = tj * 128 + wc * 64 + (lane & 15);
  if (!MASK) {
    float lm = -1e30f;
#pragma unroll
    for (int a = 0; a < 4; ++a) {
      float si[4];
#pragma unroll
      for (int r = 0; r < 4; ++r) si[r] = sqv[rbase + a * 16 + r];
#pragma unroll
      for (int b = 0; b < 4; ++b) {
        float sj = sqv[cbase + b * 16];
#pragma unroll
        for (int r = 0; r < 4; ++r)
          lm = fmaxf(lm, si[r] - 2.f * acc[a][b][r] + sj);
      }
    }
#pragma unroll
    for (int o = 32; o > 0; o >>= 1) lm = fmaxf(lm, __shfl_xor(lm, o));
    if (lane == 0) atomicMax(dmax, encf(lm));
  } else {
    float thr = 0.5f * decf(*dmax);
#pragma unroll
    for (int b = 0; b < 4; ++b) {
      int gj = cbase + b * 16;
      float sj = sqv[gj];
#pragma unroll
      for (int a = 0; a < 4; ++a) {
        int gi0 = rbase + a * 16;
        union { unsigned char c[4]; unsigned u; } m4;
#pragma unroll
        for (int r = 0; r < 4; ++r) {
          float d2v = sqv[gi0 + r] - 2.f * acc[a][b][r] + sj;
          m4.c[r] = (d2v < thr && (gi0 + r) < gj) ? 1 : 0;
        }
        *(unsigned*)(ATm + (size_t)gj * NN + gi0) = m4.u;  // AT[j][i..i+3]
      }
    }
  }
}

// ---------- generic fp32 GEMM: C[M,N] = A[M,K] @ B[K,N]; M%64==0, N%64==0, K%16==0 ----------
__global__ __launch_bounds__(256) void k_gemm(const float* A, const float* B, float* C,
                                              int M, int N, int K) {
  __shared__ float As[64][17];
  __shared__ float Bs[16][64];
  int t = threadIdx.x, tx = t & 15, ty = t >> 4;
  int m0 = blockIdx.y * 64, n0 = blockIdx.x * 64;
  float acc[4][4] = {};
  for (int k0 = 0; k0 < K; k0 += 16) {
#pragma unroll
    for (int q = 0; q < 4; ++q) {
      int l = t + q * 256; int r = l >> 4, c = l & 15;
      As[r][c] = A[(size_t)(m0 + r) * K + k0 + c];
    }
#pragma unroll
    for (int q = 0; q < 4; ++q) {
      int l = t + q * 256; int r = l >> 6, c = l & 63;
      Bs[r][c] = B[(size_t)(k0 + r) * N + n0 + c];
    }
    __syncthreads();
#pragma unroll
    for (int kk = 0; kk < 16; ++kk) {
      float av[4], bv[4];
#pragma unroll
      for (int u = 0; u < 4; ++u) { av[u] = As[ty * 4 + u][kk]; bv[u] = Bs[kk][tx * 4 + u]; }
#pragma unroll
      for (int a = 0; a < 4; ++a)
#pragma unroll
        for (int b2 = 0; b2 < 4; ++b2) acc[a][b2] = fmaf(av[a], bv[b2], acc[a][b2]);
    }
    __syncthreads();
  }
#pragma unroll
  for (int a = 0; a < 4; ++a)
#pragma unroll
    for (int b2 = 0; b2 < 4; ++b2)
      C[(size_t)(m0 + ty * 4 + a) * N + n0 + tx * 4 + b2] = acc[a][b2];
}

// ---------- dinv[j] = 1/sqrt(1 + sum_i AT[j][i]) ----------
__global__ __launch_bounds__(256) void k_deg(const unsigned char* ATm, float* dinv, int n) {
  int w = threadIdx.x >> 6, lane = threadIdx.x & 63;
  int j = blockIdx.x * 4 + w;
  if (j >= n) return;
  const uint4* row = (const uint4*)(ATm + (size_t)j * n);
  int sum = 0;
  for (int p = lane; p < n / 16; p += 64) {
    uint4 v = row[p];
    unsigned a = v.x, b = v.y, c = v.z, d = v.w;
    sum += (a & 0xff) + ((a >> 8) & 0xff) + ((a >> 16) & 0xff) + (a >> 24);
    sum += (b & 0xff) + ((b >> 8) & 0xff) + ((b >> 16) & 0xff) + (b >> 24);
    sum += (c & 0xff) + ((c >> 8) & 0xff) + ((c >> 16) & 0xff) + (c >> 24);
    sum += (d & 0xff) + ((d >> 8) & 0xff) + ((d >> 16) & 0xff) + (d >> 24);
  }
  for (int s = 32; s > 0; s >>= 1) sum += __shfl_down(sum, s);
  if (lane == 0) dinv[j] = 1.f / sqrtf((float)(1 + sum));
}

// ---------- y[i][c] = dinv[i] * xW[i][c] ----------
__global__ void k_y(const float* xW, const float* dinv, float* y, int n) {
  int t = blockIdx.x * 256 + threadIdx.x;
  if (t < n * 256) y[t] = dinv[t >> 8] * xW[t];
}

// ---------- out[j][c] = relu(dinv[j]*(y[j][c] + sum_{i:AT[j,i]} y[i][c]) + b[c]) ----------
__global__ __launch_bounds__(256) void k_agg(const float* y, const unsigned char* ATm,
                                             const float* dinv, const float* bias,
                                             float* out, int n) {
  __shared__ unsigned char mrow[256];
  __shared__ int s_any;
  int j = blockIdx.x, t = threadIdx.x;
  float acc = y[(size_t)j * 256 + t];
  for (int i0 = 0; i0 < n; i0 += 256) {
    if (t == 0) s_any = 0;
    __syncthreads();
    unsigned char m = ATm[(size_t)j * n + i0 + t];
    mrow[t] = m;
    if (m) s_any = 1;
    __syncthreads();
    if (s_any) {
      for (int u = 0; u < 256; ++u)
        if (mrow[u]) acc += y[(size_t)(i0 + u) * 256 + t];
    }
    __syncthreads();
  }
  float o = dinv[j] * acc + bias[t];
  out[(size_t)j * 256 + t] = fmaxf(o, 0.f);
}

// ---------- y2[i] = dinv[i] * dot(xg[i], Wpool) ----------
__global__ __launch_bounds__(256) void k_xwp(const float* xg, const float* Wp,
                                             const float* dinv, float* y2, int n) {
  int w = threadIdx.x >> 6, lane = threadIdx.x & 63;
  int i = blockIdx.x * 4 + w;
  if (i >= n) return;
  float s = 0.f;
#pragma unroll
  for (int q = 0; q < 4; ++q) { int c = lane + q * 64; s += xg[(size_t)i * 256 + c] * Wp[c]; }
  for (int sh = 32; sh > 0; sh >>= 1) s += __shfl_down(s, sh);
  if (lane == 0) y2[i] = dinv[i] * s;
}

// ---------- score[j] = tanh(dinv[j]*(y2[j] + sum_{i:AT[j,i]} y2[i]) + bpool) ----------
__global__ __launch_bounds__(256) void k_scorek(const float* y2, const unsigned char* ATm,
                                                const float* dinv, const float* bp,
                                                float* score, int n) {
  int w = threadIdx.x >> 6, lane = threadIdx.x & 63;
  int j = blockIdx.x * 4 + w;
  if (j >= n) return;
  const unsigned char* row = ATm + (size_t)j * n;
  float s = 0.f;
  for (int i = lane; i < n; i += 64)
    if (row[i]) s += y2[i];
  for (int sh = 32; sh > 0; sh >>= 1) s += __shfl_down(s, sh);
  if (lane == 0) score[j] = tanhf(dinv[j] * (y2[j] + s) + bp[0]);
}

// ---------- radix-select top-k (exact PyG set semantics; output in index order) ----------
__global__ __launch_bounds__(1024) void k_topsel(const float* score, int n, int k,
                                                 int* perm, float* vals) {
  __shared__ unsigned keys[4096];
  __shared__ unsigned hist[256];
  __shared__ unsigned s_state[2];  // [0]=prefix(cutoff), [1]=need(ties to take)
  __shared__ unsigned woff[16];
  int t = threadIdx.x, lane = t & 63, w = t >> 6;
  for (int i = t; i < 4096; i += 1024) keys[i] = (i < n) ? encf(score[i]) : 0u;
  if (t == 0) { s_state[0] = 0u; s_state[1] = (unsigned)k; }
  __syncthreads();

  // 4 MSB-first radix passes to find the k-th largest key exactly
  for (int pass = 0; pass < 4; ++pass) {
    int shift = 24 - pass * 8;
    if (t < 256) hist[t] = 0u;
    __syncthreads();
    unsigned prefix = s_state[0];
    unsigned need = s_state[1];
    unsigned pmask = pass ? (0xFFFFFFFFu << (shift + 8)) : 0u;
    for (int i = t; i < n; i += 1024) {
      unsigned kk = keys[i];
      if ((kk & pmask) == prefix) atomicAdd(&hist[(kk >> shift) & 255u], 1u);
    }
    __syncthreads();
    if (w == 0) {
      unsigned h[4], suf[4];
#pragma unroll
      for (int r = 0; r < 4; ++r) h[r] = hist[lane * 4 + r];
      suf[3] = h[3]; suf[2] = h[2] + suf[3]; suf[1] = h[1] + suf[2]; suf[0] = h[0] + suf[1];
      unsigned lsum = suf[0];
      unsigned s = lsum;  // inclusive suffix-sum across lanes
#pragma unroll
      for (int off = 1; off < 64; off <<= 1) {
        unsigned o = __shfl_down(s, off);
        if (lane + off < 64) s += o;
      }
      unsigned Hl = s - lsum;  // contribution of lanes > lane
      int cand = -1; unsigned cumAt = 0, histAt = 0;
#pragma unroll
      for (int r = 0; r < 4; ++r) {
        unsigned c = Hl + suf[r];  // cum(4*lane+r) = count of keys with digit >= d
        if (c >= need) { cand = lane * 4 + r; cumAt = c; histAt = h[r]; }
      }
      int gmax = cand;
#pragma unroll
      for (int off = 32; off > 0; off >>= 1) {
        int o = __shfl_xor(gmax, off);
        gmax = o > gmax ? o : gmax;
      }
      if (cand == gmax && cand >= 0) {
        s_state[0] = prefix | ((unsigned)cand << shift);
        s_state[1] = need - (cumAt - histAt);  // minus count of strictly-larger digits
      }
    }
    __syncthreads();
  }
  unsigned cutoff = s_state[0];
  unsigned tcount = s_state[1];
  unsigned G = (unsigned)k - tcount;  // count of keys strictly > cutoff

  // compaction in index order: 4 contiguous elements per thread.
  int i0 = t * 4;
  unsigned loc[4], cnt = 0;
#pragma unroll
  for (int r = 0; r < 4; ++r) {
    unsigned kk = keys[i0 + r];
    unsigned g = (kk > cutoff) ? 1u : 0u;
    unsigned e = (kk == cutoff) ? 1u : 0u;
    loc[r] = cnt;
    cnt += (g << 16) | e;
  }
  unsigned inc = cnt;  // wave inclusive scan
#pragma unroll
  for (int off = 1; off < 64; off <<= 1) {
    unsigned o = __shfl_up(inc, off);
    if (lane >= off) inc += o;
  }
  if (lane == 63) woff[w] = inc;
  __syncthreads();
  if (t == 0) {
    unsigned run = 0;
    for (int q = 0; q < 16; ++q) { unsigned v = woff[q]; woff[q] = run; run += v; }
  }
  __syncthreads();
  unsigned base = woff[w] + (inc - cnt);
#pragma unroll
  for (int r = 0; r < 4; ++r) {
    unsigned kk = keys[i0 + r];
    unsigned p = base + loc[r];
    if (kk > cutoff) {
      unsigned pos = p >> 16;
      perm[pos] = i0 + r; vals[pos] = decf(kk);
    } else if (kk == cutoff) {
      unsigned pe = p & 0xffffu;
      if (pe < tcount) { perm[G + pe] = i0 + r; vals[G + pe] = decf(kk); }
    }
  }
}

// ---------- xp[r][c] = xg[perm[r]][c] * vals[r] ----------
__global__ void k_gatherx(const float* xg, const int* perm, const float* vals,
                          float* xp, int k) {
  int t = blockIdx.x * 256 + threadIdx.x;
  if (t >= k * 256) return;
  int r = t >> 8, c = t & 255;
  xp[t] = xg[(size_t)perm[r] * 256 + c] * vals[r];
}

// ---------- ATnew[c][r] = ATold[perm[c]][perm[r]] ----------
__global__ __launch_bounds__(256) void k_gatherA(const unsigned char* ATold, const int* perm,
                                                 unsigned char* ATnew, int nold, int kn) {
  __shared__ int sperm[4096];
  int t = threadIdx.x, c = blockIdx.x;
  for (int r = t; r < kn; r += 256) sperm[r] = perm[r];
  __syncthreads();
  const unsigned char* row = ATold + (size_t)sperm[c] * nold;
  unsigned char* orow = ATnew + (size_t)c * kn;
  for (int r = t; r < kn; r += 256) orow[r] = row[sperm[r]];
}

// ---------- readout partials / final ----------
__global__ __launch_bounds__(256) void k_rpart(const float* xp, float* pmax, float* psum, int k) {
  int b = blockIdx.x, t = threadIdx.x;
  float m = -1e30f, s = 0.f;
  for (int r = b; r < k; r += 16) { float v = xp[(size_t)r * 256 + t]; m = fmaxf(m, v); s += v; }
  pmax[b * 256 + t] = m; psum[b * 256 + t] = s;
}
__global__ void k_rfin(const float* pmax, const float* psum, float* out, int k) {
  int t = threadIdx.x;
  float m = -1e30f, s = 0.f;
  for (int q = 0; q < 16; ++q) { m = fmaxf(m, pmax[q * 256 + t]); s += psum[q * 256 + t]; }
  out[t] += m;
  out[256 + t] += s / (float)k;
}

// ---------- host-side layer driver ----------
static void run_layer(hipStream_t stream, const float* x_in, int n, int inC,
                      const float* W, const float* b, const float* Wpool, const float* bpool,
                      int k, const unsigned char* ATcur, unsigned char* ATnext,
                      float* xW, float* ybuf, float* xg, float* xp, float* dinv, float* y2,
                      float* score, int* perm, float* vals, float* pmax, float* psum, float* out) {
  k_deg<<<n / 4, 256, 0, stream>>>(ATcur, dinv, n);
  k_gemm<<<dim3(256 / 64, n / 64), 256, 0, stream>>>(x_in, W, xW, n, 256, inC);
  k_y<<<n, 256, 0, stream>>>(xW, dinv, ybuf, n);
  k_agg<<<n, 256, 0, stream>>>(ybuf, ATcur, dinv, b, xg, n);
  k_xwp<<<n / 4, 256, 0, stream>>>(xg, Wpool, dinv, y2, n);
  k_scorek<<<n / 4, 256, 0, stream>>>(y2, ATcur, dinv, bpool, score, n);
  k_topsel<<<1, 1024, 0, stream>>>(score, n, k, perm, vals);
  k_gatherx<<<k, 256, 0, stream>>>(xg, perm, vals, xp, k);
  k_rpart<<<16, 256, 0, stream>>>(xp, pmax, psum, k);
  k_rfin<<<1, 256, 0, stream>>>(pmax, psum, out, k);
  if (ATnext) k_gatherA<<<k, 256, 0, stream>>>(ATcur, perm, ATnext, n, k);
}

extern "C" void kernel_launch(void* const* d_in, const int* in_sizes, int n_in,
                              void* d_out, int out_size, void* d_ws, size_t ws_size,
                              hipStream_t stream) {
  const float* feature = (const float*)d_in[0];
  const float* img     = (const float*)d_in[1];
  const float* Wp      = (const float*)d_in[2];
  const float* bp      = (const float*)d_in[3];
  const float* ln_f_g  = (const float*)d_in[4];
  const float* ln_f_b  = (const float*)d_in[5];
  const float* ln_p_g  = (const float*)d_in[6];
  const float* ln_p_b  = (const float*)d_in[7];
  const float* W1 = (const float*)d_in[8];   const float* b1 = (const float*)d_in[9];
  const float* Wpool1 = (const float*)d_in[10]; const float* bpool1 = (const float*)d_in[11];
  const float* W2 = (const float*)d_in[12];  const float* b2 = (const float*)d_in[13];
  const float* Wpool2 = (const float*)d_in[14]; const float* bpool2 = (const float*)d_in[15];
  const float* W3 = (const float*)d_in[16];  const float* b3 = (const float*)d_in[17];
  const float* Wpool3 = (const float*)d_in[18]; const float* bpool3 = (const float*)d_in[19];
  float* out = (float*)d_out;
  (void)in_sizes; (void)n_in; (void)out_size; (void)ws_size;

  char* w = (char*)d_ws;
  size_t off = 0;
  auto alloc = [&](size_t bytes) -> char* {
    off = (off + 255) & ~(size_t)255;
    char* p = w + off;
    off += bytes;
    return p;
  };
  float* pos0 = (float*)alloc((size_t)NN * 12 * 4);
  float* pos1 = (float*)alloc((size_t)NN * 12 * 4);
  float* x0   = (float*)alloc((size_t)NN * 512 * 4);
  unsigned short* x0h = (unsigned short*)alloc((size_t)NN * 512 * 2);
  float* sqv  = (float*)alloc((size_t)NN * 4);
  unsigned* dmax = (unsigned*)alloc(4);
  float* dinv = (float*)alloc((size_t)NN * 4);
  float* xW   = (float*)alloc((size_t)NN * 256 * 4);
  float* ybuf = (float*)alloc((size_t)NN * 256 * 4);
  float* xg   = (float*)alloc((size_t)NN * 256 * 4);
  float* xp   = (float*)alloc((size_t)NN * 256 * 4);
  float* y2   = (float*)alloc((size_t)NN * 4);
  float* score= (float*)alloc((size_t)NN * 4);
  int*   perm = (int*)alloc((size_t)NN * 4);
  float* vals = (float*)alloc((size_t)NN * 4);
  float* pmax = (float*)alloc(16 * 256 * 4);
  float* psum = (float*)alloc(16 * 256 * 4);
  unsigned char* ATa = (unsigned char*)alloc((size_t)NN * NN);
  unsigned char* ATb = (unsigned char*)alloc((size_t)3072 * 3072);

  // preamble
  k_init<<<2, 256, 0, stream>>>(out, dmax);
  k_pos<<<(NN * 12 + 255) / 256, 256, 0, stream>>>(img, Wp, bp, pos0);
  k_attn2<<<NN / 8, 256, 0, stream>>>(pos0, pos1);
  k_lnf<<<NN, 256, 0, stream>>>(feature, ln_f_g, ln_f_b, x0);
  k_lnp<<<NN / 256, 256, 0, stream>>>(pos1, ln_p_g, ln_p_b, x0);
  k_sq<<<NN, 256, 0, stream>>>(x0, sqv);
  k_cvt<<<NN * 512 / 4 / 256, 256, 0, stream>>>(x0, x0h);

  // edge construction via MFMA: max pass, then mask pass (upper 128-tile pairs)
  const int NT = NN / 128, TT = NT * (NT + 1) / 2;
  k_d2m<false><<<TT, 256, 0, stream>>>(x0h, sqv, dmax, nullptr);
  hipMemsetAsync(ATa, 0, (size_t)NN * NN, stream);
  k_d2m<true><<<TT, 256, 0, stream>>>(x0h, sqv, dmax, ATa);

  // three GCN + SAGPool + readout layers
  run_layer(stream, x0, 4096, 512, W1, b1, Wpool1, bpool1, 3072, ATa, ATb,
            xW, ybuf, xg, xp, dinv, y2, score, perm, vals, pmax, psum, out);
  run_layer(stream, xp, 3072, 256, W2, b2, Wpool2, bpool2, 2304, ATb, ATa,
            xW, ybuf, xg, xp, dinv, y2, score, perm, vals, pmax, psum, out);
  run_layer(stream, xp, 2304, 256, W3, b3, Wpool3, bpool3, 1728, ATa, nullptr,
            xW, ybuf, xg, xp, dinv, y2, score, perm, vals, pmax, psum, out);
}

// Round 5
// 434.790 us; speedup vs baseline: 2.2937x; 1.1910x over previous
//
#include <hip/hip_runtime.h>
#include <math.h>

#define NN 4096
#define RB 128  // readout stage-1 blocks

typedef __attribute__((ext_vector_type(8))) short bf16x8;
typedef __attribute__((ext_vector_type(4))) float f32x4;

// ---------- helpers ----------
__device__ __forceinline__ unsigned encf(float f) {
  unsigned u = __float_as_uint(f);
  return (u & 0x80000000u) ? ~u : (u | 0x80000000u);
}
__device__ __forceinline__ float decf(unsigned u) {
  return __uint_as_float((u & 0x80000000u) ? (u ^ 0x80000000u) : ~u);
}
__device__ __forceinline__ unsigned short f2bf(float f) {
  unsigned u = __float_as_uint(f);
  return (unsigned short)((u + 0x7fffu + ((u >> 16) & 1u)) >> 16);
}

// ---------- init ----------
__global__ void k_init(float* out, unsigned* dmax) {
  int t = blockIdx.x * 256 + threadIdx.x;
  if (t < 512) out[t] = 0.f;
  if (t == 0) *dmax = 0u;
}

// ---------- pos = img @ Wp + bp ----------
__global__ void k_pos(const float* img, const float* Wp, const float* bp, float* pos) {
  int t = blockIdx.x * 256 + threadIdx.x;
  if (t >= NN * 12) return;
  int i = t / 12, d = t % 12;
  float s = bp[d];
#pragma unroll
  for (int k = 0; k < 6; ++k) s += img[i * 6 + k] * Wp[k * 12 + d];
  pos[t] = s;
}

// ---------- flash attention, d=12 ----------
__global__ __launch_bounds__(256) void k_attn2(const float* pos, float* out) {
  int t = threadIdx.x, lane = t & 63, w = t >> 6;
  int ib = blockIdx.x * 8 + w * 2;  // 2 rows per wave, 8 per block
  float pi[2][12];
#pragma unroll
  for (int i = 0; i < 2; ++i)
#pragma unroll
    for (int d = 0; d < 12; ++d) pi[i][d] = pos[(ib + i) * 12 + d] * 0.28867513459481287f;
  float ml[2] = {-1e30f, -1e30f}, sl[2] = {0.f, 0.f};
  float acc[2][12] = {};
  const float4* p4 = (const float4*)pos;
  for (int j0 = 0; j0 < NN; j0 += 64) {
    int j = j0 + lane;
    float4 a = p4[j * 3 + 0], b = p4[j * 3 + 1], c = p4[j * 3 + 2];
    float pj[12] = {a.x, a.y, a.z, a.w, b.x, b.y, b.z, b.w, c.x, c.y, c.z, c.w};
#pragma unroll
    for (int i = 0; i < 2; ++i) {
      float s = 0.f;
#pragma unroll
      for (int d = 0; d < 12; ++d) s = fmaf(pi[i][d], pj[d], s);
      if (s > ml[i]) {
        float f = expf(ml[i] - s);
        sl[i] = fmaf(sl[i], f, 1.f);
#pragma unroll
        for (int d = 0; d < 12; ++d) acc[i][d] = fmaf(acc[i][d], f, pj[d]);
        ml[i] = s;
      } else {
        float e = expf(s - ml[i]);
        sl[i] += e;
#pragma unroll
        for (int d = 0; d < 12; ++d) acc[i][d] = fmaf(e, pj[d], acc[i][d]);
      }
    }
  }
#pragma unroll
  for (int i = 0; i < 2; ++i) {
    float gm = ml[i];
#pragma unroll
    for (int o = 32; o > 0; o >>= 1) gm = fmaxf(gm, __shfl_xor(gm, o));
    float f = expf(ml[i] - gm);
    float s = sl[i] * f;
#pragma unroll
    for (int o = 32; o > 0; o >>= 1) s += __shfl_xor(s, o);
    float ad[12];
#pragma unroll
    for (int d = 0; d < 12; ++d) {
      ad[d] = acc[i][d] * f;
#pragma unroll
      for (int o = 32; o > 0; o >>= 1) ad[d] += __shfl_xor(ad[d], o);
    }
    if (lane == 0) {
      float inv = 1.f / s;
#pragma unroll
      for (int d = 0; d < 12; ++d) out[(ib + i) * 12 + d] = ad[d] * inv;
    }
  }
}

// ---------- layernorm feature (500) -> x0[:, 0:500] ----------
__global__ __launch_bounds__(256) void k_lnf(const float* f, const float* g, const float* b, float* x0) {
  __shared__ float row[500];
  __shared__ float red[256];
  int i = blockIdx.x, t = threadIdx.x;
  float ls = 0.f;
  for (int c = t; c < 500; c += 256) { float v = f[i * 500 + c]; row[c] = v; ls += v; }
  red[t] = ls; __syncthreads();
  for (int s = 128; s > 0; s >>= 1) { if (t < s) red[t] += red[t + s]; __syncthreads(); }
  float m = red[0] * (1.f / 500.f); __syncthreads();
  float lv = 0.f;
  for (int c = t; c < 500; c += 256) { float d = row[c] - m; lv += d * d; }
  red[t] = lv; __syncthreads();
  for (int s = 128; s > 0; s >>= 1) { if (t < s) red[t] += red[t + s]; __syncthreads(); }
  float var = red[0] * (1.f / 500.f);
  float scale = 1.f / sqrtf(var + 1e-5f);
  for (int c = t; c < 500; c += 256) x0[(size_t)i * 512 + c] = (row[c] - m) * scale * g[c] + b[c];
}

// ---------- layernorm pos (12) -> x0[:, 500:512] ----------
__global__ void k_lnp(const float* p, const float* g, const float* b, float* x0) {
  int i = blockIdx.x * 256 + threadIdx.x;
  if (i >= NN) return;
  float v[12], m = 0.f;
#pragma unroll
  for (int d = 0; d < 12; ++d) { v[d] = p[i * 12 + d]; m += v[d]; }
  m *= (1.f / 12.f);
  float var = 0.f;
#pragma unroll
  for (int d = 0; d < 12; ++d) { float dd = v[d] - m; var += dd * dd; }
  var *= (1.f / 12.f);
  float scale = 1.f / sqrtf(var + 1e-5f);
#pragma unroll
  for (int d = 0; d < 12; ++d) x0[(size_t)i * 512 + 500 + d] = (v[d] - m) * scale * g[d] + b[d];
}

// ---------- sq[i] = sum_c x0[i][c]^2 ----------
__global__ __launch_bounds__(256) void k_sq(const float* x0, float* sqv) {
  __shared__ float red[256];
  int i = blockIdx.x, t = threadIdx.x;
  float a = x0[(size_t)i * 512 + t], b = x0[(size_t)i * 512 + 256 + t];
  red[t] = a * a + b * b; __syncthreads();
  for (int s = 128; s > 0; s >>= 1) { if (t < s) red[t] += red[t + s]; __syncthreads(); }
  if (t == 0) sqv[i] = red[0];
}

// ---------- fp32 -> bf16 conversion (4 elems/thread) ----------
__global__ void k_cvt(const float* x, unsigned short* xh) {
  int t = blockIdx.x * 256 + threadIdx.x;  // t < NN*512/4
  float4 v = ((const float4*)x)[t];
  ushort4 h;
  h.x = f2bf(v.x); h.y = f2bf(v.y); h.z = f2bf(v.z); h.w = f2bf(v.w);
  ((ushort4*)xh)[t] = h;
}

// ---------- MFMA d2 tiles (128x128, upper tile pairs): max / mask pass ----------
#define LS 40
template <bool MASK>
__global__ __launch_bounds__(256) void k_d2m(const unsigned short* X, const float* sqv,
                                             unsigned* dmax, unsigned char* ATm) {
  __shared__ unsigned short As[128 * LS];
  __shared__ unsigned short Bs[128 * LS];
  const int NT = NN / 128;
  int bid = blockIdx.x, ti = 0, rem = bid;
  while (rem >= NT - ti) { rem -= NT - ti; ++ti; }
  int tj = ti + rem;
  int t = threadIdx.x, lane = t & 63, w = t >> 6;
  int wr = w >> 1, wc = w & 1;  // wave's 64x64 sub-tile
  f32x4 acc[4][4] = {};
  const unsigned short* Abase = X + (size_t)ti * 128 * 512;
  const unsigned short* Bbase = X + (size_t)tj * 128 * 512;
  for (int k0 = 0; k0 < 512; k0 += 32) {
    __syncthreads();
#pragma unroll
    for (int q0 = 0; q0 < 2; ++q0) {
      int q = t + q0 * 256;          // 512 16B-chunks per panel
      int r = q >> 2, c = q & 3;     // row, 16B-chunk within row
      uint4 va = *(const uint4*)(Abase + (size_t)r * 512 + k0 + c * 8);
      uint4 vb = *(const uint4*)(Bbase + (size_t)r * 512 + k0 + c * 8);
      *(uint4*)(&As[r * LS + c * 8]) = va;
      *(uint4*)(&Bs[r * LS + c * 8]) = vb;
    }
    __syncthreads();
    bf16x8 af[4], bq[4];
    int kc = (lane >> 4) * 8, rl = lane & 15;
#pragma unroll
    for (int f = 0; f < 4; ++f) {
      af[f] = *(const bf16x8*)(&As[(wr * 64 + f * 16 + rl) * LS + kc]);
      bq[f] = *(const bf16x8*)(&Bs[(wc * 64 + f * 16 + rl) * LS + kc]);
    }
#pragma unroll
    for (int a = 0; a < 4; ++a)
#pragma unroll
      for (int b = 0; b < 4; ++b)
        acc[a][b] = __builtin_amdgcn_mfma_f32_16x16x32_bf16(af[a], bq[b], acc[a][b], 0, 0, 0);
  }
  int rbase = ti * 128 + wr * 64 + ((lane >> 4) << 2);
  int cbase = tj * 128 + wc * 64 + (lane & 15);
  if (!MASK) {
    float lm = -1e30f;
#pragma unroll
    for (int a = 0; a < 4; ++a) {
      float si[4];
#pragma unroll
      for (int r = 0; r < 4; ++r) si[r] = sqv[rbase + a * 16 + r];
#pragma unroll
      for (int b = 0; b < 4; ++b) {
        float sj = sqv[cbase + b * 16];
#pragma unroll
        for (int r = 0; r < 4; ++r)
          lm = fmaxf(lm, si[r] - 2.f * acc[a][b][r] + sj);
      }
    }
#pragma unroll
    for (int o = 32; o > 0; o >>= 1) lm = fmaxf(lm, __shfl_xor(lm, o));
    if (lane == 0) atomicMax(dmax, encf(lm));
  } else {
    float thr = 0.5f * decf(*dmax);
#pragma unroll
    for (int b = 0; b < 4; ++b) {
      int gj = cbase + b * 16;
      float sj = sqv[gj];
#pragma unroll
      for (int a = 0; a < 4; ++a) {
        int gi0 = rbase + a * 16;
        union { unsigned char c[4]; unsigned u; } m4;
#pragma unroll
        for (int r = 0; r < 4; ++r) {
          float d2v = sqv[gi0 + r] - 2.f * acc[a][b][r] + sj;
          m4.c[r] = (d2v < thr && (gi0 + r) < gj) ? 1 : 0;
        }
        *(unsigned*)(ATm + (size_t)gj * NN + gi0) = m4.u;  // AT[j][i..i+3]
      }
    }
  }
}

// ---------- generic fp32 GEMM: C[M,N] = A[M,K] @ B[K,N]; M%64==0, N%64==0, K%16==0 ----------
__global__ __launch_bounds__(256) void k_gemm(const float* A, const float* B, float* C,
                                              int M, int N, int K) {
  __shared__ float As[64][17];
  __shared__ float Bs[16][64];
  int t = threadIdx.x, tx = t & 15, ty = t >> 4;
  int m0 = blockIdx.y * 64, n0 = blockIdx.x * 64;
  float acc[4][4] = {};
  for (int k0 = 0; k0 < K; k0 += 16) {
#pragma unroll
    for (int q = 0; q < 4; ++q) {
      int l = t + q * 256; int r = l >> 4, c = l & 15;
      As[r][c] = A[(size_t)(m0 + r) * K + k0 + c];
    }
#pragma unroll
    for (int q = 0; q < 4; ++q) {
      int l = t + q * 256; int r = l >> 6, c = l & 63;
      Bs[r][c] = B[(size_t)(k0 + r) * N + n0 + c];
    }
    __syncthreads();
#pragma unroll
    for (int kk = 0; kk < 16; ++kk) {
      float av[4], bv[4];
#pragma unroll
      for (int u = 0; u < 4; ++u) { av[u] = As[ty * 4 + u][kk]; bv[u] = Bs[kk][tx * 4 + u]; }
#pragma unroll
      for (int a = 0; a < 4; ++a)
#pragma unroll
        for (int b2 = 0; b2 < 4; ++b2) acc[a][b2] = fmaf(av[a], bv[b2], acc[a][b2]);
    }
    __syncthreads();
  }
#pragma unroll
  for (int a = 0; a < 4; ++a)
#pragma unroll
    for (int b2 = 0; b2 < 4; ++b2)
      C[(size_t)(m0 + ty * 4 + a) * N + n0 + tx * 4 + b2] = acc[a][b2];
}

// ---------- dinv[j] = 1/sqrt(1 + sum_i AT[j][i]) ----------
__global__ __launch_bounds__(256) void k_deg(const unsigned char* ATm, float* dinv, int n) {
  int w = threadIdx.x >> 6, lane = threadIdx.x & 63;
  int j = blockIdx.x * 4 + w;
  if (j >= n) return;
  const uint4* row = (const uint4*)(ATm + (size_t)j * n);
  int sum = 0;
  for (int p = lane; p < n / 16; p += 64) {
    uint4 v = row[p];
    unsigned a = v.x, b = v.y, c = v.z, d = v.w;
    sum += (a & 0xff) + ((a >> 8) & 0xff) + ((a >> 16) & 0xff) + (a >> 24);
    sum += (b & 0xff) + ((b >> 8) & 0xff) + ((b >> 16) & 0xff) + (b >> 24);
    sum += (c & 0xff) + ((c >> 8) & 0xff) + ((c >> 16) & 0xff) + (c >> 24);
    sum += (d & 0xff) + ((d >> 8) & 0xff) + ((d >> 16) & 0xff) + (d >> 24);
  }
  for (int s = 32; s > 0; s >>= 1) sum += __shfl_down(sum, s);
  if (lane == 0) dinv[j] = 1.f / sqrtf((float)(1 + sum));
}

// ---------- y[i][c] = dinv[i] * xW[i][c] ----------
__global__ void k_y(const float* xW, const float* dinv, float* y, int n) {
  int t = blockIdx.x * 256 + threadIdx.x;
  if (t < n * 256) y[t] = dinv[t >> 8] * xW[t];
}

// ---------- out[j][c] = relu(dinv[j]*(y[j][c] + sum_{i:AT[j,i]} y[i][c]) + b[c]) ----------
__global__ __launch_bounds__(256) void k_agg(const float* y, const unsigned char* ATm,
                                             const float* dinv, const float* bias,
                                             float* out, int n) {
  __shared__ unsigned char mrow[256];
  __shared__ int s_any;
  int j = blockIdx.x, t = threadIdx.x;
  float acc = y[(size_t)j * 256 + t];
  for (int i0 = 0; i0 < n; i0 += 256) {
    if (t == 0) s_any = 0;
    __syncthreads();
    unsigned char m = ATm[(size_t)j * n + i0 + t];
    mrow[t] = m;
    if (m) s_any = 1;
    __syncthreads();
    if (s_any) {
      for (int u = 0; u < 256; ++u)
        if (mrow[u]) acc += y[(size_t)(i0 + u) * 256 + t];
    }
    __syncthreads();
  }
  float o = dinv[j] * acc + bias[t];
  out[(size_t)j * 256 + t] = fmaxf(o, 0.f);
}

// ---------- y2[i] = dinv[i] * dot(xg[i], Wpool) ----------
__global__ __launch_bounds__(256) void k_xwp(const float* xg, const float* Wp,
                                             const float* dinv, float* y2, int n) {
  int w = threadIdx.x >> 6, lane = threadIdx.x & 63;
  int i = blockIdx.x * 4 + w;
  if (i >= n) return;
  float s = 0.f;
#pragma unroll
  for (int q = 0; q < 4; ++q) { int c = lane + q * 64; s += xg[(size_t)i * 256 + c] * Wp[c]; }
  for (int sh = 32; sh > 0; sh >>= 1) s += __shfl_down(s, sh);
  if (lane == 0) y2[i] = dinv[i] * s;
}

// ---------- score[j] = tanh(dinv[j]*(y2[j] + sum_{i:AT[j,i]} y2[i]) + bpool) ----------
__global__ __launch_bounds__(256) void k_scorek(const float* y2, const unsigned char* ATm,
                                                const float* dinv, const float* bp,
                                                float* score, int n) {
  int w = threadIdx.x >> 6, lane = threadIdx.x & 63;
  int j = blockIdx.x * 4 + w;
  if (j >= n) return;
  const unsigned char* row = ATm + (size_t)j * n;
  float s = 0.f;
  for (int i = lane; i < n; i += 64)
    if (row[i]) s += y2[i];
  for (int sh = 32; sh > 0; sh >>= 1) s += __shfl_down(s, sh);
  if (lane == 0) score[j] = tanhf(dinv[j] * (y2[j] + s) + bp[0]);
}

// ---------- radix-select top-k (exact PyG set semantics; output in index order) ----------
__global__ __launch_bounds__(1024) void k_topsel(const float* score, int n, int k,
                                                 int* perm, float* vals) {
  __shared__ unsigned keys[4096];
  __shared__ unsigned hist[256];
  __shared__ unsigned s_state[2];  // [0]=prefix(cutoff), [1]=need(ties to take)
  __shared__ unsigned woff[16];
  int t = threadIdx.x, lane = t & 63, w = t >> 6;
  for (int i = t; i < 4096; i += 1024) keys[i] = (i < n) ? encf(score[i]) : 0u;
  if (t == 0) { s_state[0] = 0u; s_state[1] = (unsigned)k; }
  __syncthreads();

  for (int pass = 0; pass < 4; ++pass) {
    int shift = 24 - pass * 8;
    if (t < 256) hist[t] = 0u;
    __syncthreads();
    unsigned prefix = s_state[0];
    unsigned need = s_state[1];
    unsigned pmask = pass ? (0xFFFFFFFFu << (shift + 8)) : 0u;
    for (int i = t; i < n; i += 1024) {
      unsigned kk = keys[i];
      if ((kk & pmask) == prefix) atomicAdd(&hist[(kk >> shift) & 255u], 1u);
    }
    __syncthreads();
    if (w == 0) {
      unsigned h[4], suf[4];
#pragma unroll
      for (int r = 0; r < 4; ++r) h[r] = hist[lane * 4 + r];
      suf[3] = h[3]; suf[2] = h[2] + suf[3]; suf[1] = h[1] + suf[2]; suf[0] = h[0] + suf[1];
      unsigned lsum = suf[0];
      unsigned s = lsum;
#pragma unroll
      for (int off = 1; off < 64; off <<= 1) {
        unsigned o = __shfl_down(s, off);
        if (lane + off < 64) s += o;
      }
      unsigned Hl = s - lsum;
      int cand = -1; unsigned cumAt = 0, histAt = 0;
#pragma unroll
      for (int r = 0; r < 4; ++r) {
        unsigned c = Hl + suf[r];
        if (c >= need) { cand = lane * 4 + r; cumAt = c; histAt = h[r]; }
      }
      int gmax = cand;
#pragma unroll
      for (int off = 32; off > 0; off >>= 1) {
        int o = __shfl_xor(gmax, off);
        gmax = o > gmax ? o : gmax;
      }
      if (cand == gmax && cand >= 0) {
        s_state[0] = prefix | ((unsigned)cand << shift);
        s_state[1] = need - (cumAt - histAt);
      }
    }
    __syncthreads();
  }
  unsigned cutoff = s_state[0];
  unsigned tcount = s_state[1];
  unsigned G = (unsigned)k - tcount;

  int i0 = t * 4;
  unsigned loc[4], cnt = 0;
#pragma unroll
  for (int r = 0; r < 4; ++r) {
    unsigned kk = keys[i0 + r];
    unsigned g = (kk > cutoff) ? 1u : 0u;
    unsigned e = (kk == cutoff) ? 1u : 0u;
    loc[r] = cnt;
    cnt += (g << 16) | e;
  }
  unsigned inc = cnt;
#pragma unroll
  for (int off = 1; off < 64; off <<= 1) {
    unsigned o = __shfl_up(inc, off);
    if (lane >= off) inc += o;
  }
  if (lane == 63) woff[w] = inc;
  __syncthreads();
  if (t == 0) {
    unsigned run = 0;
    for (int q = 0; q < 16; ++q) { unsigned v = woff[q]; woff[q] = run; run += v; }
  }
  __syncthreads();
  unsigned base = woff[w] + (inc - cnt);
#pragma unroll
  for (int r = 0; r < 4; ++r) {
    unsigned kk = keys[i0 + r];
    unsigned p = base + loc[r];
    if (kk > cutoff) {
      unsigned pos = p >> 16;
      perm[pos] = i0 + r; vals[pos] = decf(kk);
    } else if (kk == cutoff) {
      unsigned pe = p & 0xffffu;
      if (pe < tcount) { perm[G + pe] = i0 + r; vals[G + pe] = decf(kk); }
    }
  }
}

// ---------- xp[r][c] = xg[perm[r]][c] * vals[r] ----------
__global__ void k_gatherx(const float* xg, const int* perm, const float* vals,
                          float* xp, int k) {
  int t = blockIdx.x * 256 + threadIdx.x;
  if (t >= k * 256) return;
  int r = t >> 8, c = t & 255;
  xp[t] = xg[(size_t)perm[r] * 256 + c] * vals[r];
}

// ---------- ATnew[c][r] = ATold[perm[c]][perm[r]] ----------
__global__ __launch_bounds__(256) void k_gatherA(const unsigned char* ATold, const int* perm,
                                                 unsigned char* ATnew, int nold, int kn) {
  __shared__ int sperm[4096];
  int t = threadIdx.x, c = blockIdx.x;
  for (int r = t; r < kn; r += 256) sperm[r] = perm[r];
  __syncthreads();
  const unsigned char* row = ATold + (size_t)sperm[c] * nold;
  unsigned char* orow = ATnew + (size_t)c * kn;
  for (int r = t; r < kn; r += 256) orow[r] = row[sperm[r]];
}

// ---------- readout partials (RB blocks) / final ----------
__global__ __launch_bounds__(256) void k_rpart(const float* xp, float* pmax, float* psum, int k) {
  int b = blockIdx.x, t = threadIdx.x;
  float m = -1e30f, s = 0.f;
  for (int r = b; r < k; r += RB) { float v = xp[(size_t)r * 256 + t]; m = fmaxf(m, v); s += v; }
  pmax[b * 256 + t] = m; psum[b * 256 + t] = s;
}
__global__ void k_rfin(const float* pmax, const float* psum, float* out, int k) {
  int t = threadIdx.x;
  float m = -1e30f, s = 0.f;
  for (int q = 0; q < RB; ++q) { m = fmaxf(m, pmax[q * 256 + t]); s += psum[q * 256 + t]; }
  out[t] += m;
  out[256 + t] += s / (float)k;
}

// ---------- host-side layer driver ----------
static void run_layer(hipStream_t stream, const float* x_in, int n, int inC,
                      const float* W, const float* b, const float* Wpool, const float* bpool,
                      int k, const unsigned char* ATcur, unsigned char* ATnext,
                      float* xW, float* ybuf, float* xg, float* xp, float* dinv, float* y2,
                      float* score, int* perm, float* vals, float* pmax, float* psum, float* out) {
  k_deg<<<n / 4, 256, 0, stream>>>(ATcur, dinv, n);
  k_gemm<<<dim3(256 / 64, n / 64), 256, 0, stream>>>(x_in, W, xW, n, 256, inC);
  k_y<<<n, 256, 0, stream>>>(xW, dinv, ybuf, n);
  k_agg<<<n, 256, 0, stream>>>(ybuf, ATcur, dinv, b, xg, n);
  k_xwp<<<n / 4, 256, 0, stream>>>(xg, Wpool, dinv, y2, n);
  k_scorek<<<n / 4, 256, 0, stream>>>(y2, ATcur, dinv, bpool, score, n);
  k_topsel<<<1, 1024, 0, stream>>>(score, n, k, perm, vals);
  k_gatherx<<<k, 256, 0, stream>>>(xg, perm, vals, xp, k);
  k_rpart<<<RB, 256, 0, stream>>>(xp, pmax, psum, k);
  k_rfin<<<1, 256, 0, stream>>>(pmax, psum, out, k);
  if (ATnext) k_gatherA<<<k, 256, 0, stream>>>(ATcur, perm, ATnext, n, k);
}

extern "C" void kernel_launch(void* const* d_in, const int* in_sizes, int n_in,
                              void* d_out, int out_size, void* d_ws, size_t ws_size,
                              hipStream_t stream) {
  const float* feature = (const float*)d_in[0];
  const float* img     = (const float*)d_in[1];
  const float* Wp      = (const float*)d_in[2];
  const float* bp      = (const float*)d_in[3];
  const float* ln_f_g  = (const float*)d_in[4];
  const float* ln_f_b  = (const float*)d_in[5];
  const float* ln_p_g  = (const float*)d_in[6];
  const float* ln_p_b  = (const float*)d_in[7];
  const float* W1 = (const float*)d_in[8];   const float* b1 = (const float*)d_in[9];
  const float* Wpool1 = (const float*)d_in[10]; const float* bpool1 = (const float*)d_in[11];
  const float* W2 = (const float*)d_in[12];  const float* b2 = (const float*)d_in[13];
  const float* Wpool2 = (const float*)d_in[14]; const float* bpool2 = (const float*)d_in[15];
  const float* W3 = (const float*)d_in[16];  const float* b3 = (const float*)d_in[17];
  const float* Wpool3 = (const float*)d_in[18]; const float* bpool3 = (const float*)d_in[19];
  float* out = (float*)d_out;
  (void)in_sizes; (void)n_in; (void)out_size; (void)ws_size;

  char* w = (char*)d_ws;
  size_t off = 0;
  auto alloc = [&](size_t bytes) -> char* {
    off = (off + 255) & ~(size_t)255;
    char* p = w + off;
    off += bytes;
    return p;
  };
  float* pos0 = (float*)alloc((size_t)NN * 12 * 4);
  float* pos1 = (float*)alloc((size_t)NN * 12 * 4);
  float* x0   = (float*)alloc((size_t)NN * 512 * 4);
  unsigned short* x0h = (unsigned short*)alloc((size_t)NN * 512 * 2);
  float* sqv  = (float*)alloc((size_t)NN * 4);
  unsigned* dmax = (unsigned*)alloc(4);
  float* dinv = (float*)alloc((size_t)NN * 4);
  float* xW   = (float*)alloc((size_t)NN * 256 * 4);
  float* ybuf = (float*)alloc((size_t)NN * 256 * 4);
  float* xg   = (float*)alloc((size_t)NN * 256 * 4);
  float* xp   = (float*)alloc((size_t)NN * 256 * 4);
  float* y2   = (float*)alloc((size_t)NN * 4);
  float* score= (float*)alloc((size_t)NN * 4);
  int*   perm = (int*)alloc((size_t)NN * 4);
  float* vals = (float*)alloc((size_t)NN * 4);
  float* pmax = (float*)alloc(RB * 256 * 4);
  float* psum = (float*)alloc(RB * 256 * 4);
  unsigned char* ATa = (unsigned char*)alloc((size_t)NN * NN);
  unsigned char* ATb = (unsigned char*)alloc((size_t)3072 * 3072);

  // preamble
  k_init<<<2, 256, 0, stream>>>(out, dmax);
  k_pos<<<(NN * 12 + 255) / 256, 256, 0, stream>>>(img, Wp, bp, pos0);
  k_attn2<<<NN / 8, 256, 0, stream>>>(pos0, pos1);
  k_lnf<<<NN, 256, 0, stream>>>(feature, ln_f_g, ln_f_b, x0);
  k_lnp<<<NN / 256, 256, 0, stream>>>(pos1, ln_p_g, ln_p_b, x0);
  k_sq<<<NN, 256, 0, stream>>>(x0, sqv);
  k_cvt<<<NN * 512 / 4 / 256, 256, 0, stream>>>(x0, x0h);

  // edge construction via MFMA: max pass, then mask pass (upper 128-tile pairs)
  const int NT = NN / 128, TT = NT * (NT + 1) / 2;
  k_d2m<false><<<TT, 256, 0, stream>>>(x0h, sqv, dmax, nullptr);
  hipMemsetAsync(ATa, 0, (size_t)NN * NN, stream);
  k_d2m<true><<<TT, 256, 0, stream>>>(x0h, sqv, dmax, ATa);

  // three GCN + SAGPool + readout layers
  run_layer(stream, x0, 4096, 512, W1, b1, Wpool1, bpool1, 3072, ATa, ATb,
            xW, ybuf, xg, xp, dinv, y2, score, perm, vals, pmax, psum, out);
  run_layer(stream, xp, 3072, 256, W2, b2, Wpool2, bpool2, 2304, ATb, ATa,
            xW, ybuf, xg, xp, dinv, y2, score, perm, vals, pmax, psum, out);
  run_layer(stream, xp, 2304, 256, W3, b3, Wpool3, bpool3, 1728, ATa, nullptr,
            xW, ybuf, xg, xp, dinv, y2, score, perm, vals, pmax, psum, out);
}